// Round 1
// baseline (698.317 us; speedup 1.0000x reference)
//
#include <hip/hip_runtime.h>
#include <hip/hip_bf16.h>
#include <math.h>

#define T_SEQ 2048

typedef __bf16 bf16x8 __attribute__((ext_vector_type(8)));
typedef float  f32x4  __attribute__((ext_vector_type(4)));

#define GLOAD_LDS16(g, l) __builtin_amdgcn_global_load_lds( \
    (const __attribute__((address_space(1))) void*)(g),      \
    (__attribute__((address_space(3))) void*)(l), 16, 0, 0)

// ---------------- fp32 -> bf16 cast (8 el/thread) ----------------
__global__ __launch_bounds__(256) void cast_bf16(const float* __restrict__ src,
                                                 __bf16* __restrict__ dst, int n)
{
    int i = (blockIdx.x * 256 + threadIdx.x) * 8;
    if (i < n) {
        float4 a = *reinterpret_cast<const float4*>(src + i);
        float4 b = *reinterpret_cast<const float4*>(src + i + 4);
        bf16x8 f;
        f[0] = (__bf16)a.x; f[1] = (__bf16)a.y; f[2] = (__bf16)a.z; f[3] = (__bf16)a.w;
        f[4] = (__bf16)b.x; f[5] = (__bf16)b.y; f[6] = (__bf16)b.z; f[7] = (__bf16)b.w;
        *reinterpret_cast<bf16x8*>(dst + i) = f;
    }
}

// ---------------- in-place RoPE over 64-el head blocks ----------------
__global__ __launch_bounds__(256) void rope_ip(__bf16* buf, int shift, int total)
{
    int gid = blockIdx.x * 256 + threadIdx.x;
    if (gid >= total) return;
    int row = gid >> shift;
    int rem = gid & ((1 << shift) - 1);
    int hb = rem >> 5, j = rem & 31;
    int t = row & (T_SEQ - 1);
    const float L2B = 0.4152410118609203f;      // log2(10000)/32
    float freq = exp2f(-L2B * (float)j);
    float sn, cs;
    __sincosf((float)t * freq, &sn, &cs);
    size_t base = ((size_t)row << (shift + 1)) + hb * 64 + j;
    float v1 = (float)buf[base], v2 = (float)buf[base + 32];
    buf[base]      = (__bf16)(v1 * cs - v2 * sn);
    buf[base + 32] = (__bf16)(v2 * cs + v1 * sn);
}

// ---------------- V pre-transpose: vtt[bh][u][dv(128)][k(64)] XOR-swizzled ----
// Element (dv,k) stored at dv*64 + ((k>>3 ^ (dv&7))<<3) + (k&7) so a flat
// (linear-dest) global_load_lds copy in flash lands it bank-conflict-free.
__global__ __launch_bounds__(256) void prep_v(const __bf16* __restrict__ ukv,
                                              __bf16* __restrict__ vtt)
{
    __shared__ __align__(16) __bf16 Ls[64 * 136];
    const int tid = threadIdx.x;
    const int u = blockIdx.x, bh = blockIdx.y;
    const int b = bh >> 4, h = bh & 15;
    const size_t base = (size_t)b * T_SEQ + u * 64;
    #pragma unroll
    for (int p = 0; p < 4; p++) {
        int c = tid + 256 * p;
        int k = c >> 4, dv8 = (c & 15) * 8;
        *reinterpret_cast<bf16x8*>(Ls + k * 136 + dv8) =
            *reinterpret_cast<const bf16x8*>(ukv + (base + k) * 4096 + h * 256 + 128 + dv8);
    }
    __syncthreads();
    #pragma unroll
    for (int p = 0; p < 4; p++) {
        int c = tid + 256 * p;
        int dv = c >> 3, kb = c & 7;
        bf16x8 f;
        #pragma unroll
        for (int i = 0; i < 8; i++) f[i] = Ls[(kb * 8 + i) * 136 + dv];
        *reinterpret_cast<bf16x8*>(vtt + (((size_t)bh * 32 + u) * 128 + dv) * 64
                                   + ((kb ^ (dv & 7)) << 3)) = f;
    }
}

// ---------------- bf16 MFMA GEMM: C[M,N] = A[M,K] @ B[N,K]^T ----------------
template <typename OutT>
__global__ __launch_bounds__(256) void gemm_bt_mfma(const __bf16* __restrict__ A,
                                                    const __bf16* __restrict__ B,
                                                    OutT* __restrict__ C,
                                                    int M, int N, int K)
{
    __shared__ __align__(16) __bf16 As[128 * 32];
    __shared__ __align__(16) __bf16 Bs[128 * 32];
    const int tid  = threadIdx.x;
    const int lane = tid & 63, w = tid >> 6;
    const int l15  = lane & 15, quad = lane >> 4;
    const int wm = w >> 1, wn = w & 1;
    const int m0 = blockIdx.y * 128, n0 = blockIdx.x * 128;

    const int srow = lane >> 2;
    const int scol = (lane & 3) * 8;
    const __bf16* Ap0 = A + (size_t)(m0 + 32 * w + srow) * K + scol;
    const __bf16* Ap1 = Ap0 + (size_t)16 * K;
    int bn = n0 + 32 * w + srow;
    const __bf16* Bp0 = B + (size_t)(bn      < N ? bn      : N - 1) * K + scol;
    const __bf16* Bp1 = B + (size_t)(bn + 16 < N ? bn + 16 : N - 1) * K + scol;
    __bf16* AsW = As + w * 1024 + lane * 8;
    __bf16* BsW = Bs + w * 1024 + lane * 8;

    f32x4 acc[4][4] = {};

    for (int k0 = 0; k0 < K; k0 += 32) {
        GLOAD_LDS16(Ap0 + k0, AsW);
        GLOAD_LDS16(Ap1 + k0, AsW + 512);
        GLOAD_LDS16(Bp0 + k0, BsW);
        GLOAD_LDS16(Bp1 + k0, BsW + 512);
        __syncthreads();

        bf16x8 af[4], bfr[4];
        #pragma unroll
        for (int mi = 0; mi < 4; mi++)
            af[mi] = *reinterpret_cast<const bf16x8*>(As + (wm * 64 + mi * 16 + l15) * 32 + quad * 8);
        #pragma unroll
        for (int ni = 0; ni < 4; ni++)
            bfr[ni] = *reinterpret_cast<const bf16x8*>(Bs + (wn * 64 + ni * 16 + l15) * 32 + quad * 8);
        #pragma unroll
        for (int mi = 0; mi < 4; mi++)
            #pragma unroll
            for (int ni = 0; ni < 4; ni++)
                acc[mi][ni] = __builtin_amdgcn_mfma_f32_16x16x32_bf16(af[mi], bfr[ni], acc[mi][ni], 0, 0, 0);
        __syncthreads();
    }

    #pragma unroll
    for (int mi = 0; mi < 4; mi++) {
        #pragma unroll
        for (int ni = 0; ni < 4; ni++) {
            int col = n0 + wn * 64 + ni * 16 + l15;
            if (col < N) {
                #pragma unroll
                for (int r = 0; r < 4; r++) {
                    size_t row = m0 + wm * 64 + mi * 16 + quad * 4 + r;
                    C[row * (size_t)N + col] = (OutT)acc[mi][ni][r];
                }
            }
        }
    }
}

// ---------------- MFMA flash attention (pre-roped inputs) ----------------
// Restructured for occupancy: 64-row q-tiles -> grid 1024 blocks, LDS exactly
// 40KB (KsN 16K + KsR 8K + Vt 16K) -> 4 blocks/CU (was 2 at 62.4KB).
// Staging is global_load_lds (linear LDS dest) with the XOR-swizzle applied on
// the GLOBAL source address (rule: both-sides-or-neither); all ds_read_b128
// fragment reads then land 2-lanes/bank (free). P aliases KsN after QK (one
// extra barrier per unit). Work balance: adjacent gx pair (h, 31-h).
__global__ __launch_bounds__(256, 4) void flash_mfma(
    const __bf16* __restrict__ qbuf, const __bf16* __restrict__ qrot,
    const __bf16* __restrict__ krot, const __bf16* __restrict__ ukv,
    const __bf16* __restrict__ vtt, __bf16* __restrict__ obuf)
{
    __shared__ __align__(16) __bf16 KsN[64 * 128];   // 16KB K-nope, swizzled; P alias
    __shared__ __align__(16) __bf16 KsR[64 * 64];    // 8KB  K-rope, swizzled
    __shared__ __align__(16) __bf16 Vt[128 * 64];    // 16KB V^T,    swizzled

    const int tid  = threadIdx.x;
    const int w    = tid >> 6;
    const int lane = tid & 63;
    const int l15  = lane & 15;
    const int quad = lane >> 4;
    const int key  = l15 & 7;           // swizzle key: rows read as 16x+l15
    const int bh = blockIdx.y;
    const int hx = blockIdx.x >> 1;
    const int qi = (blockIdx.x & 1) ? (31 - hx) : hx;   // anti-correlated pair
    const int b = bh >> 4, h = bh & 15;
    const int q0 = qi * 64;
    const float SCALE = 0.07216878364870323f;   // 1/sqrt(192)

    // ---- Q fragments (A-layout), all pre-roped: pure vector loads ----
    bf16x8 qf[6];
    {
        const int q = q0 + 16 * w + l15;
        const size_t g = (size_t)b * T_SEQ + q;
        const __bf16* qrow = qbuf + g * 2048 + h * 128;
        #pragma unroll
        for (int dt = 0; dt < 4; dt++)
            qf[dt] = *reinterpret_cast<const bf16x8*>(qrow + 32 * dt + 8 * quad);
        const __bf16* qrr = qrot + g * 1024 + h * 64;
        qf[4] = *reinterpret_cast<const bf16x8*>(qrr + 8 * quad);
        qf[5] = *reinterpret_cast<const bf16x8*>(qrr + 32 + 8 * quad);
    }

    f32x4 o[8] = {};
    float m_i[4], l_i[4];
    #pragma unroll
    for (int r = 0; r < 4; r++) { m_i[r] = -INFINITY; l_i[r] = 0.f; }

    const int nunits = qi + 1;
    const size_t urow = (size_t)b * T_SEQ;
    const __bf16* vbase = vtt + (size_t)bh * 32 * 8192;

    for (int u = 0; u < nunits; u++) {
        const int k0 = 64 * u;

        // ---- stage K-nope [64][128]: linear LDS dest, pre-swizzled source ----
        #pragma unroll
        for (int p = 0; p < 4; p++) {
            int c = tid + 256 * p;
            int row = c >> 4, cb = c & 15;
            GLOAD_LDS16(ukv + (urow + k0 + row) * 4096 + h * 256 + ((cb ^ (row & 7)) << 3),
                        KsN + c * 8);
        }
        // ---- stage K-rope [64][64] ----
        #pragma unroll
        for (int p = 0; p < 2; p++) {
            int c = tid + 256 * p;
            int row = c >> 3, cb = c & 7;
            GLOAD_LDS16(krot + (urow + k0 + row) * 64 + ((cb ^ (row & 7)) << 3),
                        KsR + c * 8);
        }
        // ---- stage Vt: flat copy of pre-swizzled 16KB tile ----
        {
            const __bf16* vsrc = vbase + (size_t)u * 8192;
            #pragma unroll
            for (int p = 0; p < 4; p++) {
                int c = tid + 256 * p;
                GLOAD_LDS16(vsrc + c * 8, Vt + c * 8);
            }
        }
        __syncthreads();

        // ---- S = Q K^T ----
        f32x4 s[4] = {};
        #pragma unroll
        for (int kt = 0; kt < 4; kt++) {
            const int krow = 16 * kt + l15;
            #pragma unroll
            for (int dt = 0; dt < 4; dt++) {
                bf16x8 kf = *reinterpret_cast<const bf16x8*>(
                    KsN + krow * 128 + (((4 * dt + quad) ^ key) << 3));
                s[kt] = __builtin_amdgcn_mfma_f32_16x16x32_bf16(qf[dt], kf, s[kt], 0, 0, 0);
            }
            #pragma unroll
            for (int rb = 0; rb < 2; rb++) {
                bf16x8 kf = *reinterpret_cast<const bf16x8*>(
                    KsR + krow * 64 + (((4 * rb + quad) ^ key) << 3));
                s[kt] = __builtin_amdgcn_mfma_f32_16x16x32_bf16(qf[4 + rb], kf, s[kt], 0, 0, 0);
            }
        }
        __syncthreads();   // all KsN reads done: KsN region becomes P

        // ---- causal mask (last unit only) + online softmax; P into KsN alias ----
        __bf16* P = KsN;
        const bool domask = (u == nunits - 1);
        #pragma unroll
        for (int r = 0; r < 4; r++) {
            const int rloc = 16 * w + 4 * quad + r;
            const int q = q0 + rloc;
            const int rkey = (4 * quad + r) & 7;
            float sv[4];
            #pragma unroll
            for (int kt = 0; kt < 4; kt++) {
                float v = s[kt][r] * SCALE;
                if (domask && (k0 + 16 * kt + l15 > q)) v = -INFINITY;
                sv[kt] = v;
            }
            float rmax = fmaxf(fmaxf(sv[0], sv[1]), fmaxf(sv[2], sv[3]));
            rmax = fmaxf(rmax, __shfl_xor(rmax, 1, 64));
            rmax = fmaxf(rmax, __shfl_xor(rmax, 2, 64));
            rmax = fmaxf(rmax, __shfl_xor(rmax, 4, 64));
            rmax = fmaxf(rmax, __shfl_xor(rmax, 8, 64));
            float mnew  = fmaxf(m_i[r], rmax);
            float alpha = __expf(m_i[r] - mnew);
            m_i[r] = mnew;
            float sum = 0.f;
            #pragma unroll
            for (int kt = 0; kt < 4; kt++) {
                float pv = __expf(sv[kt] - mnew);
                sum += pv;
                // col = 16kt + l15; swizzled: cb = col>>3 = 2kt + (l15>>3)
                P[rloc * 64 + (((2 * kt + (l15 >> 3)) ^ rkey) << 3) + (l15 & 7)] = (__bf16)pv;
            }
            sum += __shfl_xor(sum, 1, 64);
            sum += __shfl_xor(sum, 2, 64);
            sum += __shfl_xor(sum, 4, 64);
            sum += __shfl_xor(sum, 8, 64);
            l_i[r] = l_i[r] * alpha + sum;
            #pragma unroll
            for (int dt = 0; dt < 8; dt++) o[dt][r] *= alpha;
        }
        // No barrier: P rows [16w,16w+16) are written and read by wave w only.

        // ---- O += P V ----
        #pragma unroll
        for (int kh = 0; kh < 2; kh++) {
            const int coff = ((4 * kh + quad) ^ key) << 3;
            bf16x8 pf = *reinterpret_cast<const bf16x8*>(P + (16 * w + l15) * 64 + coff);
            #pragma unroll
            for (int dt = 0; dt < 8; dt++) {
                bf16x8 vf = *reinterpret_cast<const bf16x8*>(Vt + (16 * dt + l15) * 64 + coff);
                o[dt] = __builtin_amdgcn_mfma_f32_16x16x32_bf16(pf, vf, o[dt], 0, 0, 0);
            }
        }
        __syncthreads();   // all P/Vt reads done before next stage overwrites
    }

    // ---- epilogue (bf16 out) ----
    #pragma unroll
    for (int r = 0; r < 4; r++) {
        const int q = q0 + 16 * w + 4 * quad + r;
        const float inv = 1.0f / l_i[r];
        size_t base = ((size_t)b * T_SEQ + q) * 2048 + h * 128;
        #pragma unroll
        for (int dt = 0; dt < 8; dt++)
            obuf[base + 16 * dt + l15] = (__bf16)(o[dt][r] * inv);
    }
}

extern "C" void kernel_launch(void* const* d_in, const int* in_sizes, int n_in,
                              void* d_out, int out_size, void* d_ws, size_t ws_size,
                              hipStream_t stream)
{
    const float* x      = (const float*)d_in[0];
    const float* w_q    = (const float*)d_in[1];
    const float* w_dkv  = (const float*)d_in[2];
    const float* w_ukv  = (const float*)d_in[3];
    const float* w_o    = (const float*)d_in[4];
    const float* w_qrot = (const float*)d_in[5];
    const float* w_krot = (const float*)d_in[6];
    float* out = (float*)d_out;

    const size_t M = 4096;
    __bf16* ws   = (__bf16*)d_ws;
    __bf16* xb   = ws;                    // 4096x2048
    __bf16* wqb  = xb   + M * 2048;       // 2048x2048
    __bf16* wdkb = wqb  + 2048 * 2048;    // 512x2048
    __bf16* wukb = wdkb + 512 * 2048;     // 4096x512
    __bf16* wob  = wukb + 4096 * 512;     // 2048x2048
    __bf16* wqrb = wob  + 2048 * 2048;    // 1024x2048
    __bf16* wkrb = wqrb + 1024 * 2048;    // 64x2048
    __bf16* qb   = wkrb + 64 * 2048;      // 4096x2048
    __bf16* qr   = qb   + M * 2048;       // 4096x1024 (roped in place)
    __bf16* kr   = qr   + M * 1024;       // 4096x64   (roped in place)
    __bf16* dkv  = kr   + M * 64;         // 4096x512
    __bf16* ukv  = dkv  + M * 512;        // 4096x4096
    __bf16* ao   = ukv  + M * 4096;       // 4096x2048
    __bf16* vtt  = ao   + M * 2048;       // 32*32*128*64 (~16.8MB) swizzled tiles

    dim3 blk(256);
    cast_bf16<<<4096, blk, 0, stream>>>(x,      xb,   4096 * 2048);
    cast_bf16<<<2048, blk, 0, stream>>>(w_q,    wqb,  2048 * 2048);
    cast_bf16<<<512,  blk, 0, stream>>>(w_dkv,  wdkb, 512 * 2048);
    cast_bf16<<<1024, blk, 0, stream>>>(w_ukv,  wukb, 4096 * 512);
    cast_bf16<<<2048, blk, 0, stream>>>(w_o,    wob,  2048 * 2048);
    cast_bf16<<<1024, blk, 0, stream>>>(w_qrot, wqrb, 1024 * 2048);
    cast_bf16<<<64,   blk, 0, stream>>>(w_krot, wkrb, 64 * 2048);

    gemm_bt_mfma<__bf16><<<dim3(16, 32), blk, 0, stream>>>(xb,  wqb,  qb,  4096, 2048, 2048);
    gemm_bt_mfma<__bf16><<<dim3(8,  32), blk, 0, stream>>>(xb,  wqrb, qr,  4096, 1024, 2048);
    gemm_bt_mfma<__bf16><<<dim3(1,  32), blk, 0, stream>>>(xb,  wkrb, kr,  4096, 64,   2048);
    gemm_bt_mfma<__bf16><<<dim3(4,  32), blk, 0, stream>>>(xb,  wdkb, dkv, 4096, 512,  2048);
    gemm_bt_mfma<__bf16><<<dim3(32, 32), blk, 0, stream>>>(dkv, wukb, ukv, 4096, 4096, 512);

    rope_ip<<<8192, blk, 0, stream>>>(qr, 9, 4096 * 512);   // 16 heads * 32 pairs
    rope_ip<<<512,  blk, 0, stream>>>(kr, 5, 4096 * 32);    // 1 block  * 32 pairs
    prep_v<<<dim3(32, 32), blk, 0, stream>>>(ukv, vtt);

    flash_mfma<<<dim3(32, 32), blk, 0, stream>>>(qb, qr, kr, ukv, vtt, ao);
    gemm_bt_mfma<float><<<dim3(16, 32), blk, 0, stream>>>(ao, wob, out, 4096, 2048, 2048);
}

// Round 2
// 614.524 us; speedup vs baseline: 1.1364x; 1.1364x over previous
//
#include <hip/hip_runtime.h>
#include <hip/hip_bf16.h>
#include <math.h>

#define T_SEQ 2048

typedef __bf16 bf16x8 __attribute__((ext_vector_type(8)));
typedef float  f32x4  __attribute__((ext_vector_type(4)));

#define GLOAD_LDS16(g, l) __builtin_amdgcn_global_load_lds( \
    (const __attribute__((address_space(1))) void*)(g),      \
    (__attribute__((address_space(3))) void*)(l), 16, 0, 0)

#define VMCNT(n) asm volatile("s_waitcnt vmcnt(" #n ")" ::: "memory")

// ---------------- fp32 -> bf16 cast (8 el/thread) ----------------
__global__ __launch_bounds__(256) void cast_bf16(const float* __restrict__ src,
                                                 __bf16* __restrict__ dst, int n)
{
    int i = (blockIdx.x * 256 + threadIdx.x) * 8;
    if (i < n) {
        float4 a = *reinterpret_cast<const float4*>(src + i);
        float4 b = *reinterpret_cast<const float4*>(src + i + 4);
        bf16x8 f;
        f[0] = (__bf16)a.x; f[1] = (__bf16)a.y; f[2] = (__bf16)a.z; f[3] = (__bf16)a.w;
        f[4] = (__bf16)b.x; f[5] = (__bf16)b.y; f[6] = (__bf16)b.z; f[7] = (__bf16)b.w;
        *reinterpret_cast<bf16x8*>(dst + i) = f;
    }
}

// ---------------- in-place RoPE over 64-el head blocks ----------------
__global__ __launch_bounds__(256) void rope_ip(__bf16* buf, int shift, int total)
{
    int gid = blockIdx.x * 256 + threadIdx.x;
    if (gid >= total) return;
    int row = gid >> shift;
    int rem = gid & ((1 << shift) - 1);
    int hb = rem >> 5, j = rem & 31;
    int t = row & (T_SEQ - 1);
    const float L2B = 0.4152410118609203f;      // log2(10000)/32
    float freq = exp2f(-L2B * (float)j);
    float sn, cs;
    __sincosf((float)t * freq, &sn, &cs);
    size_t base = ((size_t)row << (shift + 1)) + hb * 64 + j;
    float v1 = (float)buf[base], v2 = (float)buf[base + 32];
    buf[base]      = (__bf16)(v1 * cs - v2 * sn);
    buf[base + 32] = (__bf16)(v2 * cs + v1 * sn);
}

// ---------------- V pre-transpose: vtt[bh][u][dv(128)][k(64), stride 72] ----
__global__ __launch_bounds__(256) void prep_v(const __bf16* __restrict__ ukv,
                                              __bf16* __restrict__ vtt)
{
    __shared__ __align__(16) __bf16 Ls[64 * 136];
    const int tid = threadIdx.x;
    const int u = blockIdx.x, bh = blockIdx.y;
    const int b = bh >> 4, h = bh & 15;
    const size_t base = (size_t)b * T_SEQ + u * 64;
    #pragma unroll
    for (int p = 0; p < 4; p++) {
        int c = tid + 256 * p;
        int k = c >> 4, dv8 = (c & 15) * 8;
        *reinterpret_cast<bf16x8*>(Ls + k * 136 + dv8) =
            *reinterpret_cast<const bf16x8*>(ukv + (base + k) * 4096 + h * 256 + 128 + dv8);
    }
    __syncthreads();
    #pragma unroll
    for (int p = 0; p < 4; p++) {
        int c = tid + 256 * p;
        int dv = c >> 3, k8 = (c & 7) * 8;
        bf16x8 f;
        #pragma unroll
        for (int i = 0; i < 8; i++) f[i] = Ls[(k8 + i) * 136 + dv];
        *reinterpret_cast<bf16x8*>(vtt + (((size_t)bh * 32 + u) * 128 + dv) * 72 + k8) = f;
    }
}

// ---------------- bf16 MFMA GEMM (128^2 tile): C[M,N] = A[M,K] @ B[N,K]^T ----
template <typename OutT>
__global__ __launch_bounds__(256) void gemm_bt_mfma(const __bf16* __restrict__ A,
                                                    const __bf16* __restrict__ B,
                                                    OutT* __restrict__ C,
                                                    int M, int N, int K)
{
    __shared__ __align__(16) __bf16 As[128 * 32];
    __shared__ __align__(16) __bf16 Bs[128 * 32];
    const int tid  = threadIdx.x;
    const int lane = tid & 63, w = tid >> 6;
    const int l15  = lane & 15, quad = lane >> 4;
    const int wm = w >> 1, wn = w & 1;
    const int m0 = blockIdx.y * 128, n0 = blockIdx.x * 128;

    const int srow = lane >> 2;
    const int scol = (lane & 3) * 8;
    const __bf16* Ap0 = A + (size_t)(m0 + 32 * w + srow) * K + scol;
    const __bf16* Ap1 = Ap0 + (size_t)16 * K;
    int bn = n0 + 32 * w + srow;
    const __bf16* Bp0 = B + (size_t)(bn      < N ? bn      : N - 1) * K + scol;
    const __bf16* Bp1 = B + (size_t)(bn + 16 < N ? bn + 16 : N - 1) * K + scol;
    __bf16* AsW = As + w * 1024 + lane * 8;
    __bf16* BsW = Bs + w * 1024 + lane * 8;

    f32x4 acc[4][4] = {};

    for (int k0 = 0; k0 < K; k0 += 32) {
        GLOAD_LDS16(Ap0 + k0, AsW);
        GLOAD_LDS16(Ap1 + k0, AsW + 512);
        GLOAD_LDS16(Bp0 + k0, BsW);
        GLOAD_LDS16(Bp1 + k0, BsW + 512);
        __syncthreads();

        bf16x8 af[4], bfr[4];
        #pragma unroll
        for (int mi = 0; mi < 4; mi++)
            af[mi] = *reinterpret_cast<const bf16x8*>(As + (wm * 64 + mi * 16 + l15) * 32 + quad * 8);
        #pragma unroll
        for (int ni = 0; ni < 4; ni++)
            bfr[ni] = *reinterpret_cast<const bf16x8*>(Bs + (wn * 64 + ni * 16 + l15) * 32 + quad * 8);
        #pragma unroll
        for (int mi = 0; mi < 4; mi++)
            #pragma unroll
            for (int ni = 0; ni < 4; ni++)
                acc[mi][ni] = __builtin_amdgcn_mfma_f32_16x16x32_bf16(af[mi], bfr[ni], acc[mi][ni], 0, 0, 0);
        __syncthreads();
    }

    #pragma unroll
    for (int mi = 0; mi < 4; mi++) {
        #pragma unroll
        for (int ni = 0; ni < 4; ni++) {
            int col = n0 + wn * 64 + ni * 16 + l15;
            if (col < N) {
                #pragma unroll
                for (int r = 0; r < 4; r++) {
                    size_t row = m0 + wm * 64 + mi * 16 + quad * 4 + r;
                    C[row * (size_t)N + col] = (OutT)acc[mi][ni][r];
                }
            }
        }
    }
}

// ---------------- 8-phase counted-vmcnt GEMM (T2+T3+T4+T5) ------------------
// BM=128 BN=256 BK=64, 512 thr, 8 waves (2M x 4N), per-wave 64x64 output.
// LDS 96KB: 2 dbuf x {A 128x64 split in 2 row-bit5 halves, B 256x64 in 2}.
// Swizzle: 16B-seg ^= (lds_row & 7), applied on gload_lds GLOBAL source
// (linear LDS dest) and on ds_read addresses -> 2-way conflicts only (free).
// Per tile: 4 quadrant phases (mh,nh); stage next tile's halves in order
// Ah0,Bh0,Bh1,Ah1; waits VMCNT(2)/(3)/-/(3) each cover the NEXT phase's reads
// (issue-to-wait distance >= 3 phases); vmcnt never drained to 0 in the loop.
template <typename OutT>
__global__ __launch_bounds__(512) void gemm_bt_8ph(const __bf16* __restrict__ A,
                                                   const __bf16* __restrict__ B,
                                                   OutT* __restrict__ C,
                                                   int M, int N, int K)
{
    __shared__ __align__(16) __bf16 S[2 * 24576];   // 96KB
    const int tid  = threadIdx.x;
    const int lane = tid & 63;
    const int w    = tid >> 6;
    const int l15  = lane & 15, quad = lane >> 4;
    const int wm = w >> 2, wn = w & 3;
    const int m0 = blockIdx.y * 128, n0 = blockIdx.x * 256;
    const int NT = K >> 6;

    f32x4 acc[4][4] = {};

    // staging: A-half = 1 gload_lds/thread, B-half = 2.
    const int lrA = tid >> 3, segA = tid & 7;

    auto stageA = [&](int T1, int h) {
        int d = T1 & 1;
        int g = ((lrA >> 5) << 6) + h * 32 + (lrA & 31);
        GLOAD_LDS16(A + (size_t)(m0 + g) * K + T1 * 64 + ((segA ^ (lrA & 7)) << 3),
                    S + d * 24576 + h * 4096 + tid * 8);
    };
    auto stageB = [&](int T1, int h) {
        int d = T1 & 1;
        #pragma unroll
        for (int i = 0; i < 2; i++) {
            int c = i * 512 + tid;
            int lr = c >> 3, seg = c & 7;
            int g = ((lr >> 5) << 6) + h * 32 + (lr & 31);
            GLOAD_LDS16(B + (size_t)(n0 + g) * K + T1 * 64 + ((seg ^ (lr & 7)) << 3),
                        S + d * 24576 + 8192 + h * 8192 + c * 8);
        }
    };

#define PHASE(d, mh, nh, STAGE, WAIT) do {                                     \
    const __bf16* Ah_ = S + (d) * 24576 + (mh) * 4096;                         \
    const __bf16* Bh_ = S + (d) * 24576 + 8192 + (nh) * 8192;                  \
    bf16x8 af[2][2], bfr[2][2];                                                \
    _Pragma("unroll")                                                          \
    for (int mr = 0; mr < 2; mr++) {                                           \
        int ar = wm * 32 + mr * 16 + l15;                                      \
        _Pragma("unroll")                                                      \
        for (int kk = 0; kk < 2; kk++)                                         \
            af[mr][kk] = *reinterpret_cast<const bf16x8*>(                     \
                Ah_ + ar * 64 + (((kk * 4 + quad) ^ (ar & 7)) << 3));          \
    }                                                                          \
    _Pragma("unroll")                                                          \
    for (int nr = 0; nr < 2; nr++) {                                           \
        int br = wn * 32 + nr * 16 + l15;                                      \
        _Pragma("unroll")                                                      \
        for (int kk = 0; kk < 2; kk++)                                         \
            bfr[nr][kk] = *reinterpret_cast<const bf16x8*>(                    \
                Bh_ + br * 64 + (((kk * 4 + quad) ^ (br & 7)) << 3));          \
    }                                                                          \
    STAGE;                                                                     \
    WAIT;                                                                      \
    __builtin_amdgcn_s_barrier();                                              \
    asm volatile("s_waitcnt lgkmcnt(0)" ::: "memory");                         \
    __builtin_amdgcn_sched_barrier(0);                                         \
    __builtin_amdgcn_s_setprio(1);                                             \
    _Pragma("unroll")                                                          \
    for (int mr = 0; mr < 2; mr++)                                             \
        _Pragma("unroll")                                                      \
        for (int nr = 0; nr < 2; nr++)                                         \
            _Pragma("unroll")                                                  \
            for (int kk = 0; kk < 2; kk++)                                     \
                acc[(mh) * 2 + mr][(nh) * 2 + nr] =                            \
                    __builtin_amdgcn_mfma_f32_16x16x32_bf16(                   \
                        af[mr][kk], bfr[nr][kk],                               \
                        acc[(mh) * 2 + mr][(nh) * 2 + nr], 0, 0, 0);           \
    __builtin_amdgcn_s_setprio(0);                                             \
} while (0)

    // prologue: stage tile 0 (order Ah0,Bh0,Bh1,Ah1 = 6 vmem instrs/wave)
    stageA(0, 0);
    stageB(0, 0);
    stageB(0, 1);
    stageA(0, 1);
    VMCNT(3);                      // Ah0,Bh0 landed; Bh1,Ah1 may be in flight
    __builtin_amdgcn_s_barrier();

    for (int T = 0; T < NT - 1; T++) {
        const int d = T & 1;
        PHASE(d, 0, 0, stageA(T + 1, 0), VMCNT(2));
        PHASE(d, 0, 1, stageB(T + 1, 0), VMCNT(3));
        PHASE(d, 1, 0, stageB(T + 1, 1), (void)0);
        PHASE(d, 1, 1, stageA(T + 1, 1), VMCNT(3));
    }
    {   // tail tile: no staging; drain progressively
        const int d = (NT - 1) & 1;
        PHASE(d, 0, 0, (void)0, VMCNT(1));
        PHASE(d, 0, 1, (void)0, VMCNT(0));
        PHASE(d, 1, 0, (void)0, (void)0);
        PHASE(d, 1, 1, (void)0, (void)0);
    }
#undef PHASE

    #pragma unroll
    for (int ai = 0; ai < 4; ai++) {
        #pragma unroll
        for (int bj = 0; bj < 4; bj++) {
            int col = n0 + wn * 64 + bj * 16 + l15;
            #pragma unroll
            for (int r = 0; r < 4; r++) {
                size_t row = m0 + wm * 64 + ai * 16 + quad * 4 + r;
                C[row * (size_t)N + col] = (OutT)acc[ai][bj][r];
            }
        }
    }
}

// ---------------- MFMA flash attention (pre-roped inputs) ----------------
// qbuf (4096,2048) head h cols h*128; qrot ROPED (4096,1024) h*64;
// krot ROPED (4096,64); ukv (4096,4096) K at h*256; vtt tiled transposed V.
// Grid (16,32): 512 blocks, one 128-row q-tile each; anti-correlated qi
// mapping so co-resident blocks sum to ~constant work; 2 blocks/CU (62.5KB LDS).
__global__ __launch_bounds__(256, 2) void flash_mfma(
    const __bf16* __restrict__ qbuf, const __bf16* __restrict__ qrot,
    const __bf16* __restrict__ krot, const __bf16* __restrict__ ukv,
    const __bf16* __restrict__ vtt, __bf16* __restrict__ obuf)
{
    constexpr int KS = 200;
    constexpr int VS = 72;
    constexpr int PS = 72;
    __shared__ __align__(16) __bf16 Ks[64 * KS];
    __shared__ __align__(16) __bf16 Vt[128 * VS];
    __shared__ __align__(16) __bf16 Psh[128 * PS];

    const int tid  = threadIdx.x;
    const int w    = tid >> 6;
    const int lane = tid & 63;
    const int l15  = lane & 15;
    const int quad = lane >> 4;
    const int gx = blockIdx.x, gy = blockIdx.y;
    int bh, qi;
    if (gy < 16) { bh = gy * 2;        qi = gx; }
    else         { bh = (gy - 16) * 2 + 1; qi = 15 - gx; }
    const int b = bh >> 4, h = bh & 15;
    const int q0 = qi * 128;
    const float SCALE = 0.07216878364870323f;   // 1/sqrt(192)

    // ---- Q fragments (A-layout), all pre-roped: pure vector loads ----
    bf16x8 qf[2][6];
    #pragma unroll
    for (int rt = 0; rt < 2; rt++) {
        const int q = q0 + 32 * w + 16 * rt + l15;
        const size_t g = (size_t)b * T_SEQ + q;
        const __bf16* qrow = qbuf + g * 2048 + h * 128;
        #pragma unroll
        for (int dt = 0; dt < 4; dt++)
            qf[rt][dt] = *reinterpret_cast<const bf16x8*>(qrow + 32 * dt + 8 * quad);
        const __bf16* qrr = qrot + g * 1024 + h * 64;
        qf[rt][4] = *reinterpret_cast<const bf16x8*>(qrr + 8 * quad);
        qf[rt][5] = *reinterpret_cast<const bf16x8*>(qrr + 32 + 8 * quad);
    }

    f32x4 o[2][8];
    float m_i[2][4], l_i[2][4];
    #pragma unroll
    for (int rt = 0; rt < 2; rt++) {
        #pragma unroll
        for (int dt = 0; dt < 8; dt++) { o[rt][dt][0]=0.f; o[rt][dt][1]=0.f; o[rt][dt][2]=0.f; o[rt][dt][3]=0.f; }
        #pragma unroll
        for (int r = 0; r < 4; r++) { m_i[rt][r] = -INFINITY; l_i[rt][r] = 0.f; }
    }

    const int nunits = 2 * qi + 2;
    const size_t urow = (size_t)b * T_SEQ;
    for (int u = 0; u < nunits; u++) {
        const int k0 = 64 * u;

        // ---- stage K nope [k][0..127]: coalesced vector copies ----
        #pragma unroll
        for (int p = 0; p < 4; p++) {
            int c = tid + 256 * p;
            int row = c >> 4, seg = (c & 15) * 8;
            *reinterpret_cast<bf16x8*>(Ks + row * KS + seg) =
                *reinterpret_cast<const bf16x8*>(ukv + (urow + k0 + row) * 4096 + h * 256 + seg);
        }
        // ---- stage K rope [k][128..191]: pre-roped, contiguous copy ----
        #pragma unroll
        for (int p = 0; p < 2; p++) {
            int c = tid + 256 * p;
            int row = c >> 3, seg = (c & 7) * 8;
            *reinterpret_cast<bf16x8*>(Ks + row * KS + 128 + seg) =
                *reinterpret_cast<const bf16x8*>(krot + (urow + k0 + row) * 64 + seg);
        }
        // ---- stage Vt: flat 18KB copy from pre-transposed tile ----
        {
            const uint4* vsrc = reinterpret_cast<const uint4*>(vtt + ((size_t)bh * 32 + u) * (128 * VS));
            uint4* vdst = reinterpret_cast<uint4*>(Vt);
            for (int c = tid; c < 1152; c += 256) vdst[c] = vsrc[c];
        }
        __syncthreads();

        // ---- S = Q K^T ----
        f32x4 s[2][4] = {};
        #pragma unroll
        for (int kt = 0; kt < 4; kt++) {
            #pragma unroll
            for (int dt = 0; dt < 6; dt++) {
                bf16x8 kf = *reinterpret_cast<const bf16x8*>(Ks + (16 * kt + l15) * KS + 32 * dt + 8 * quad);
                s[0][kt] = __builtin_amdgcn_mfma_f32_16x16x32_bf16(qf[0][dt], kf, s[0][kt], 0, 0, 0);
                s[1][kt] = __builtin_amdgcn_mfma_f32_16x16x32_bf16(qf[1][dt], kf, s[1][kt], 0, 0, 0);
            }
        }

        // ---- causal mask (only near-diagonal units) + online softmax ----
        const bool domask = (u + 2 >= nunits);
        #pragma unroll
        for (int rt = 0; rt < 2; rt++) {
            #pragma unroll
            for (int r = 0; r < 4; r++) {
                const int q = q0 + 32 * w + 16 * rt + 4 * quad + r;
                float sv[4];
                #pragma unroll
                for (int kt = 0; kt < 4; kt++) {
                    float v = s[rt][kt][r] * SCALE;
                    if (domask && (k0 + 16 * kt + l15 > q)) v = -INFINITY;
                    sv[kt] = v;
                }
                float rmax = fmaxf(fmaxf(sv[0], sv[1]), fmaxf(sv[2], sv[3]));
                rmax = fmaxf(rmax, __shfl_xor(rmax, 1, 64));
                rmax = fmaxf(rmax, __shfl_xor(rmax, 2, 64));
                rmax = fmaxf(rmax, __shfl_xor(rmax, 4, 64));
                rmax = fmaxf(rmax, __shfl_xor(rmax, 8, 64));
                float mnew  = fmaxf(m_i[rt][r], rmax);
                float alpha = __expf(m_i[rt][r] - mnew);
                m_i[rt][r] = mnew;
                float sum = 0.f;
                #pragma unroll
                for (int kt = 0; kt < 4; kt++) {
                    float pv = __expf(sv[kt] - mnew);
                    sum += pv;
                    Psh[(32 * w + 16 * rt + 4 * quad + r) * PS + 16 * kt + l15] = (__bf16)pv;
                }
                sum += __shfl_xor(sum, 1, 64);
                sum += __shfl_xor(sum, 2, 64);
                sum += __shfl_xor(sum, 4, 64);
                sum += __shfl_xor(sum, 8, 64);
                l_i[rt][r] = l_i[rt][r] * alpha + sum;
                #pragma unroll
                for (int dt = 0; dt < 8; dt++) o[rt][dt][r] *= alpha;
            }
        }
        // No barrier: Psh rows [32w,32w+32) are written and read by wave w only.

        // ---- O += P V ----
        #pragma unroll
        for (int kh = 0; kh < 2; kh++) {
            bf16x8 pf0 = *reinterpret_cast<const bf16x8*>(Psh + (32 * w + l15) * PS + 32 * kh + 8 * quad);
            bf16x8 pf1 = *reinterpret_cast<const bf16x8*>(Psh + (32 * w + 16 + l15) * PS + 32 * kh + 8 * quad);
            #pragma unroll
            for (int dt = 0; dt < 8; dt++) {
                bf16x8 vf = *reinterpret_cast<const bf16x8*>(Vt + (16 * dt + l15) * VS + 32 * kh + 8 * quad);
                o[0][dt] = __builtin_amdgcn_mfma_f32_16x16x32_bf16(pf0, vf, o[0][dt], 0, 0, 0);
                o[1][dt] = __builtin_amdgcn_mfma_f32_16x16x32_bf16(pf1, vf, o[1][dt], 0, 0, 0);
            }
        }
        __syncthreads();   // all reads of Ks/Vt done before next stage
    }

    // ---- epilogue (bf16 out) ----
    #pragma unroll
    for (int rt = 0; rt < 2; rt++) {
        #pragma unroll
        for (int r = 0; r < 4; r++) {
            const int q = q0 + 32 * w + 16 * rt + 4 * quad + r;
            const float inv = 1.0f / l_i[rt][r];
            size_t base = ((size_t)b * T_SEQ + q) * 2048 + h * 128;
            #pragma unroll
            for (int dt = 0; dt < 8; dt++)
                obuf[base + 16 * dt + l15] = (__bf16)(o[rt][dt][r] * inv);
        }
    }
}

extern "C" void kernel_launch(void* const* d_in, const int* in_sizes, int n_in,
                              void* d_out, int out_size, void* d_ws, size_t ws_size,
                              hipStream_t stream)
{
    const float* x      = (const float*)d_in[0];
    const float* w_q    = (const float*)d_in[1];
    const float* w_dkv  = (const float*)d_in[2];
    const float* w_ukv  = (const float*)d_in[3];
    const float* w_o    = (const float*)d_in[4];
    const float* w_qrot = (const float*)d_in[5];
    const float* w_krot = (const float*)d_in[6];
    float* out = (float*)d_out;

    const size_t M = 4096;
    __bf16* ws   = (__bf16*)d_ws;
    __bf16* xb   = ws;                    // 4096x2048
    __bf16* wqb  = xb   + M * 2048;       // 2048x2048
    __bf16* wdkb = wqb  + 2048 * 2048;    // 512x2048
    __bf16* wukb = wdkb + 512 * 2048;     // 4096x512
    __bf16* wob  = wukb + 4096 * 512;     // 2048x2048
    __bf16* wqrb = wob  + 2048 * 2048;    // 1024x2048
    __bf16* wkrb = wqrb + 1024 * 2048;    // 64x2048
    __bf16* qb   = wkrb + 64 * 2048;      // 4096x2048
    __bf16* qr   = qb   + M * 2048;       // 4096x1024 (roped in place)
    __bf16* kr   = qr   + M * 1024;       // 4096x64   (roped in place)
    __bf16* dkv  = kr   + M * 64;         // 4096x512
    __bf16* ukv  = dkv  + M * 512;        // 4096x4096
    __bf16* ao   = ukv  + M * 4096;       // 4096x2048
    __bf16* vtt  = ao   + M * 2048;       // 32*32*128*72 (~18.9MB)  total ~143MB

    dim3 blk(256);
    cast_bf16<<<4096, blk, 0, stream>>>(x,      xb,   4096 * 2048);
    cast_bf16<<<2048, blk, 0, stream>>>(w_q,    wqb,  2048 * 2048);
    cast_bf16<<<512,  blk, 0, stream>>>(w_dkv,  wdkb, 512 * 2048);
    cast_bf16<<<1024, blk, 0, stream>>>(w_ukv,  wukb, 4096 * 512);
    cast_bf16<<<2048, blk, 0, stream>>>(w_o,    wob,  2048 * 2048);
    cast_bf16<<<1024, blk, 0, stream>>>(w_qrot, wqrb, 1024 * 2048);
    cast_bf16<<<64,   blk, 0, stream>>>(w_krot, wkrb, 64 * 2048);

    gemm_bt_8ph<__bf16><<<dim3(8, 32),  dim3(512), 0, stream>>>(xb,  wqb,  qb,  4096, 2048, 2048);
    gemm_bt_mfma<__bf16><<<dim3(8,  32), blk, 0, stream>>>(xb,  wqrb, qr,  4096, 1024, 2048);
    gemm_bt_mfma<__bf16><<<dim3(1,  32), blk, 0, stream>>>(xb,  wkrb, kr,  4096, 64,   2048);
    gemm_bt_mfma<__bf16><<<dim3(4,  32), blk, 0, stream>>>(xb,  wdkb, dkv, 4096, 512,  2048);
    gemm_bt_8ph<__bf16><<<dim3(16, 32), dim3(512), 0, stream>>>(dkv, wukb, ukv, 4096, 4096, 512);

    rope_ip<<<8192, blk, 0, stream>>>(qr, 9, 4096 * 512);   // 16 heads * 32 pairs
    rope_ip<<<512,  blk, 0, stream>>>(kr, 5, 4096 * 32);    // 1 block  * 32 pairs
    prep_v<<<dim3(32, 32), blk, 0, stream>>>(ukv, vtt);

    flash_mfma<<<dim3(16, 32), blk, 0, stream>>>(qb, qr, kr, ukv, vtt, ao);
    gemm_bt_8ph<float><<<dim3(8, 32), dim3(512), 0, stream>>>(ao, wob, out, 4096, 2048, 2048);
}

// Round 4
// 456.299 us; speedup vs baseline: 1.5304x; 1.3468x over previous
//
#include <hip/hip_runtime.h>
#include <hip/hip_bf16.h>
#include <math.h>

#define T_SEQ 2048
#define QSTR  3648   // combined q|qrot|krot|dkv row stride

typedef __bf16 bf16x8 __attribute__((ext_vector_type(8)));
typedef float  f32x4  __attribute__((ext_vector_type(4)));

#define GLOAD_LDS16(g, l) __builtin_amdgcn_global_load_lds( \
    (const __attribute__((address_space(1))) void*)(g),      \
    (__attribute__((address_space(3))) void*)(l), 16, 0, 0)

#define VMCNT(n) asm volatile("s_waitcnt vmcnt(" #n ")" ::: "memory")

// ---------------- fp32 -> bf16 cast (8 el/thread) ----------------
__global__ __launch_bounds__(256) void cast_bf16(const float* __restrict__ src,
                                                 __bf16* __restrict__ dst, int n)
{
    int i = (blockIdx.x * 256 + threadIdx.x) * 8;
    if (i < n) {
        float4 a = *reinterpret_cast<const float4*>(src + i);
        float4 b = *reinterpret_cast<const float4*>(src + i + 4);
        bf16x8 f;
        f[0] = (__bf16)a.x; f[1] = (__bf16)a.y; f[2] = (__bf16)a.z; f[3] = (__bf16)a.w;
        f[4] = (__bf16)b.x; f[5] = (__bf16)b.y; f[6] = (__bf16)b.z; f[7] = (__bf16)b.w;
        *reinterpret_cast<bf16x8*>(dst + i) = f;
    }
}

// ---------------- in-place RoPE over 64-el head blocks (strided rows) -------
__global__ __launch_bounds__(256) void rope_ip(__bf16* buf, int shift, int stride,
                                               int total)
{
    int gid = blockIdx.x * 256 + threadIdx.x;
    if (gid >= total) return;
    int row = gid >> shift;
    int rem = gid & ((1 << shift) - 1);
    int hb = rem >> 5, j = rem & 31;
    int t = row & (T_SEQ - 1);
    const float L2B = 0.4152410118609203f;      // log2(10000)/32
    float freq = exp2f(-L2B * (float)j);
    float sn, cs;
    __sincosf((float)t * freq, &sn, &cs);
    size_t base = (size_t)row * stride + hb * 64 + j;
    float v1 = (float)buf[base], v2 = (float)buf[base + 32];
    buf[base]      = (__bf16)(v1 * cs - v2 * sn);
    buf[base + 32] = (__bf16)(v2 * cs + v1 * sn);
}

// ---------------- V pre-transpose: vtt[bh][u][dv(128)][k(64), stride 72] ----
__global__ __launch_bounds__(256) void prep_v(const __bf16* __restrict__ ukv,
                                              __bf16* __restrict__ vtt)
{
    __shared__ __align__(16) __bf16 Ls[64 * 136];
    const int tid = threadIdx.x;
    const int u = blockIdx.x, bh = blockIdx.y;
    const int b = bh >> 4, h = bh & 15;
    const size_t base = (size_t)b * T_SEQ + u * 64;
    #pragma unroll
    for (int p = 0; p < 4; p++) {
        int c = tid + 256 * p;
        int k = c >> 4, dv8 = (c & 15) * 8;
        *reinterpret_cast<bf16x8*>(Ls + k * 136 + dv8) =
            *reinterpret_cast<const bf16x8*>(ukv + (base + k) * 4096 + h * 256 + 128 + dv8);
    }
    __syncthreads();
    #pragma unroll
    for (int p = 0; p < 4; p++) {
        int c = tid + 256 * p;
        int dv = c >> 3, k8 = (c & 7) * 8;
        bf16x8 f;
        #pragma unroll
        for (int i = 0; i < 8; i++) f[i] = Ls[(k8 + i) * 136 + dv];
        *reinterpret_cast<bf16x8*>(vtt + (((size_t)bh * 32 + u) * 128 + dv) * 72 + k8) = f;
    }
}

// ---------------- 8-phase counted-vmcnt GEMM (T2+T3+T4+T5) ------------------
// BM=128 BN=256 BK=64, 512 thr, 8 waves (2M x 4N), per-wave 64x64 output.
// A row stride = lda (supports strided sub-views); B row stride = K.
// B rows clamped to N-1 and C cols guarded (supports N not multiple of 256).
template <typename OutT>
__global__ __launch_bounds__(512) void gemm_bt_8ph(const __bf16* __restrict__ A,
                                                   int lda,
                                                   const __bf16* __restrict__ B,
                                                   OutT* __restrict__ C,
                                                   int M, int N, int K)
{
    __shared__ __align__(16) __bf16 S[2 * 24576];   // 96KB
    const int tid  = threadIdx.x;
    const int lane = tid & 63;
    const int w    = tid >> 6;
    const int l15  = lane & 15, quad = lane >> 4;
    const int wm = w >> 2, wn = w & 3;
    const int m0 = blockIdx.y * 128, n0 = blockIdx.x * 256;
    const int NT = K >> 6;

    f32x4 acc[4][4] = {};

    const int lrA = tid >> 3, segA = tid & 7;

    auto stageA = [&](int T1, int h) {
        int d = T1 & 1;
        int g = ((lrA >> 5) << 6) + h * 32 + (lrA & 31);
        GLOAD_LDS16(A + (size_t)(m0 + g) * lda + T1 * 64 + ((segA ^ (lrA & 7)) << 3),
                    S + d * 24576 + h * 4096 + tid * 8);
    };
    auto stageB = [&](int T1, int h) {
        int d = T1 & 1;
        #pragma unroll
        for (int i = 0; i < 2; i++) {
            int c = i * 512 + tid;
            int lr = c >> 3, seg = c & 7;
            int g = n0 + ((lr >> 5) << 6) + h * 32 + (lr & 31);
            if (g >= N) g = N - 1;
            GLOAD_LDS16(B + (size_t)g * K + T1 * 64 + ((seg ^ (lr & 7)) << 3),
                        S + d * 24576 + 8192 + h * 8192 + c * 8);
        }
    };

#define PHASE(d, mh, nh, STAGE, WAIT) do {                                     \
    const __bf16* Ah_ = S + (d) * 24576 + (mh) * 4096;                         \
    const __bf16* Bh_ = S + (d) * 24576 + 8192 + (nh) * 8192;                  \
    bf16x8 af[2][2], bfr[2][2];                                                \
    _Pragma("unroll")                                                          \
    for (int mr = 0; mr < 2; mr++) {                                           \
        int ar = wm * 32 + mr * 16 + l15;                                      \
        _Pragma("unroll")                                                      \
        for (int kk = 0; kk < 2; kk++)                                         \
            af[mr][kk] = *reinterpret_cast<const bf16x8*>(                     \
                Ah_ + ar * 64 + (((kk * 4 + quad) ^ (ar & 7)) << 3));          \
    }                                                                          \
    _Pragma("unroll")                                                          \
    for (int nr = 0; nr < 2; nr++) {                                           \
        int br = wn * 32 + nr * 16 + l15;                                      \
        _Pragma("unroll")                                                      \
        for (int kk = 0; kk < 2; kk++)                                         \
            bfr[nr][kk] = *reinterpret_cast<const bf16x8*>(                    \
                Bh_ + br * 64 + (((kk * 4 + quad) ^ (br & 7)) << 3));          \
    }                                                                          \
    STAGE;                                                                     \
    WAIT;                                                                      \
    __builtin_amdgcn_s_barrier();                                              \
    asm volatile("s_waitcnt lgkmcnt(0)" ::: "memory");                         \
    __builtin_amdgcn_sched_barrier(0);                                         \
    __builtin_amdgcn_s_setprio(1);                                             \
    _Pragma("unroll")                                                          \
    for (int mr = 0; mr < 2; mr++)                                             \
        _Pragma("unroll")                                                      \
        for (int nr = 0; nr < 2; nr++)                                         \
            _Pragma("unroll")                                                  \
            for (int kk = 0; kk < 2; kk++)                                     \
                acc[(mh) * 2 + mr][(nh) * 2 + nr] =                            \
                    __builtin_amdgcn_mfma_f32_16x16x32_bf16(                   \
                        af[mr][kk], bfr[nr][kk],                               \
                        acc[(mh) * 2 + mr][(nh) * 2 + nr], 0, 0, 0);           \
    __builtin_amdgcn_s_setprio(0);                                             \
} while (0)

    stageA(0, 0);
    stageB(0, 0);
    stageB(0, 1);
    stageA(0, 1);
    VMCNT(3);
    __builtin_amdgcn_s_barrier();

    for (int T = 0; T < NT - 1; T++) {
        const int d = T & 1;
        PHASE(d, 0, 0, stageA(T + 1, 0), VMCNT(2));
        PHASE(d, 0, 1, stageB(T + 1, 0), VMCNT(3));
        PHASE(d, 1, 0, stageB(T + 1, 1), (void)0);
        PHASE(d, 1, 1, stageA(T + 1, 1), VMCNT(3));
    }
    {
        const int d = (NT - 1) & 1;
        PHASE(d, 0, 0, (void)0, VMCNT(1));
        PHASE(d, 0, 1, (void)0, VMCNT(0));
        PHASE(d, 1, 0, (void)0, (void)0);
        PHASE(d, 1, 1, (void)0, (void)0);
    }
#undef PHASE

    #pragma unroll
    for (int ai = 0; ai < 4; ai++) {
        #pragma unroll
        for (int bj = 0; bj < 4; bj++) {
            int col = n0 + wn * 64 + bj * 16 + l15;
            if (col < N) {
                #pragma unroll
                for (int r = 0; r < 4; r++) {
                    size_t row = m0 + wm * 64 + ai * 16 + quad * 4 + r;
                    C[row * (size_t)N + col] = (OutT)acc[ai][bj][r];
                }
            }
        }
    }
}

// ---------------- MFMA flash attention (pre-roped inputs) ----------------
// qcat (4096, QSTR): cols [0,2048) q by head; [2048,3072) roped qrot;
// [3072,3136) roped krot. ukv (4096,4096): K-nope at h*256. vtt: transposed V.
// R3 changes vs R0 structure: (1) async-STAGE split — unit u+1's K/V global
// loads issue right after QK^T (regs), ds_write after end-of-unit barrier;
// (2) l-sum deferred — per-lane partial, single shuffle-reduce in epilogue;
// (3) rmax shuffle reduce stage-major across all 8 rows (pipelined chains);
// (4) setprio around MFMA clusters.
__global__ __launch_bounds__(256, 2) void flash_mfma(
    const __bf16* __restrict__ qcat, const __bf16* __restrict__ ukv,
    const __bf16* __restrict__ vtt, __bf16* __restrict__ obuf)
{
    constexpr int KS = 200;
    constexpr int VS = 72;
    constexpr int PS = 72;
    __shared__ __align__(16) __bf16 Ks[64 * KS];
    __shared__ __align__(16) __bf16 Vt[128 * VS];
    __shared__ __align__(16) __bf16 Psh[128 * PS];

    const int tid  = threadIdx.x;
    const int w    = tid >> 6;
    const int lane = tid & 63;
    const int l15  = lane & 15;
    const int quad = lane >> 4;
    const int gx = blockIdx.x, gy = blockIdx.y;
    int bh, qi;
    if (gy < 16) { bh = gy * 2;            qi = gx; }
    else         { bh = (gy - 16) * 2 + 1; qi = 15 - gx; }
    const int b = bh >> 4, h = bh & 15;
    const int q0 = qi * 128;
    const float SCALE = 0.07216878364870323f;   // 1/sqrt(192)
    const __bf16* qrot = qcat + 2048;
    const __bf16* krot = qcat + 3072;

    // ---- Q fragments (A-layout), all pre-roped: pure vector loads ----
    bf16x8 qf[2][6];
    #pragma unroll
    for (int rt = 0; rt < 2; rt++) {
        const int q = q0 + 32 * w + 16 * rt + l15;
        const size_t g = (size_t)b * T_SEQ + q;
        const __bf16* qrow = qcat + g * QSTR + h * 128;
        #pragma unroll
        for (int dt = 0; dt < 4; dt++)
            qf[rt][dt] = *reinterpret_cast<const bf16x8*>(qrow + 32 * dt + 8 * quad);
        const __bf16* qrr = qrot + g * QSTR + h * 64;
        qf[rt][4] = *reinterpret_cast<const bf16x8*>(qrr + 8 * quad);
        qf[rt][5] = *reinterpret_cast<const bf16x8*>(qrr + 32 + 8 * quad);
    }

    f32x4 o[2][8] = {};
    float m_i[2][4], l_i[2][4];
    #pragma unroll
    for (int rt = 0; rt < 2; rt++)
        #pragma unroll
        for (int r = 0; r < 4; r++) { m_i[rt][r] = -INFINITY; l_i[rt][r] = 0.f; }

    const int nunits = 2 * qi + 2;
    const size_t urow = (size_t)b * T_SEQ;

    // ---- register staging buffers (async-STAGE split) ----
    bf16x8 kn[4];     // K-nope 64x128
    bf16x8 krp[2];    // K-rope 64x64
    uint4  vv[5];     // Vt 128x72 (1152 uint4; threads<128 carry a 5th)

    auto load_unit = [&](int u) {
        const size_t roff = urow + 64 * u;
        #pragma unroll
        for (int p = 0; p < 4; p++) {
            int c = tid + 256 * p;
            int row = c >> 4, seg = (c & 15) * 8;
            kn[p] = *reinterpret_cast<const bf16x8*>(
                ukv + (roff + row) * 4096 + h * 256 + seg);
        }
        #pragma unroll
        for (int p = 0; p < 2; p++) {
            int c = tid + 256 * p;
            int row = c >> 3, seg = (c & 7) * 8;
            krp[p] = *reinterpret_cast<const bf16x8*>(
                krot + (roff + row) * QSTR + seg);
        }
        const uint4* vsrc = reinterpret_cast<const uint4*>(
            vtt + ((size_t)bh * 32 + u) * (128 * VS));
        #pragma unroll
        for (int j = 0; j < 4; j++) vv[j] = vsrc[tid + 256 * j];
        if (tid < 128) vv[4] = vsrc[1024 + tid];
    };
    auto write_unit = [&]() {
        #pragma unroll
        for (int p = 0; p < 4; p++) {
            int c = tid + 256 * p;
            int row = c >> 4, seg = (c & 15) * 8;
            *reinterpret_cast<bf16x8*>(Ks + row * KS + seg) = kn[p];
        }
        #pragma unroll
        for (int p = 0; p < 2; p++) {
            int c = tid + 256 * p;
            int row = c >> 3, seg = (c & 7) * 8;
            *reinterpret_cast<bf16x8*>(Ks + row * KS + 128 + seg) = krp[p];
        }
        uint4* vdst = reinterpret_cast<uint4*>(Vt);
        #pragma unroll
        for (int j = 0; j < 4; j++) vdst[tid + 256 * j] = vv[j];
        if (tid < 128) vdst[1024 + tid] = vv[4];
    };

    load_unit(0);
    write_unit();
    __syncthreads();

    for (int u = 0; u < nunits; u++) {
        const int k0 = 64 * u;

        // ---- S = Q K^T ----
        f32x4 s[2][4] = {};
        __builtin_amdgcn_s_setprio(1);
        #pragma unroll
        for (int kt = 0; kt < 4; kt++) {
            #pragma unroll
            for (int dt = 0; dt < 6; dt++) {
                bf16x8 kf = *reinterpret_cast<const bf16x8*>(
                    Ks + (16 * kt + l15) * KS + 32 * dt + 8 * quad);
                s[0][kt] = __builtin_amdgcn_mfma_f32_16x16x32_bf16(qf[0][dt], kf, s[0][kt], 0, 0, 0);
                s[1][kt] = __builtin_amdgcn_mfma_f32_16x16x32_bf16(qf[1][dt], kf, s[1][kt], 0, 0, 0);
            }
        }
        __builtin_amdgcn_s_setprio(0);

        // ---- issue next unit's global loads (latency hidden under softmax+PV)
        if (u + 1 < nunits) load_unit(u + 1);

        // ---- causal mask + online softmax (deferred l-sum, stage-major rmax)
        const bool domask = (u + 2 >= nunits);
        float rmax[2][4];
        #pragma unroll
        for (int rt = 0; rt < 2; rt++) {
            #pragma unroll
            for (int r = 0; r < 4; r++) {
                const int q = q0 + 32 * w + 16 * rt + 4 * quad + r;
                #pragma unroll
                for (int kt = 0; kt < 4; kt++) {
                    float v = s[rt][kt][r] * SCALE;
                    if (domask && (k0 + 16 * kt + l15 > q)) v = -INFINITY;
                    s[rt][kt][r] = v;
                }
                rmax[rt][r] = fmaxf(fmaxf(s[rt][0][r], s[rt][1][r]),
                                    fmaxf(s[rt][2][r], s[rt][3][r]));
            }
        }
        #pragma unroll
        for (int st = 1; st <= 8; st <<= 1)
            #pragma unroll
            for (int rt = 0; rt < 2; rt++)
                #pragma unroll
                for (int r = 0; r < 4; r++)
                    rmax[rt][r] = fmaxf(rmax[rt][r], __shfl_xor(rmax[rt][r], st, 64));
        #pragma unroll
        for (int rt = 0; rt < 2; rt++) {
            #pragma unroll
            for (int r = 0; r < 4; r++) {
                float mnew  = fmaxf(m_i[rt][r], rmax[rt][r]);
                float alpha = __expf(m_i[rt][r] - mnew);
                m_i[rt][r] = mnew;
                const int rloc = 32 * w + 16 * rt + 4 * quad + r;
                float part = 0.f;
                #pragma unroll
                for (int kt = 0; kt < 4; kt++) {
                    float pv = __expf(s[rt][kt][r] - mnew);
                    part += pv;
                    Psh[rloc * PS + 16 * kt + l15] = (__bf16)pv;
                }
                l_i[rt][r] = l_i[rt][r] * alpha + part;   // per-lane partial
                #pragma unroll
                for (int dt = 0; dt < 8; dt++) o[rt][dt][r] *= alpha;
            }
        }
        // No barrier: Psh rows [32w,32w+32) are written and read by wave w only.

        // ---- O += P V ----
        __builtin_amdgcn_s_setprio(1);
        #pragma unroll
        for (int kh = 0; kh < 2; kh++) {
            bf16x8 pf0 = *reinterpret_cast<const bf16x8*>(Psh + (32 * w + l15) * PS + 32 * kh + 8 * quad);
            bf16x8 pf1 = *reinterpret_cast<const bf16x8*>(Psh + (32 * w + 16 + l15) * PS + 32 * kh + 8 * quad);
            #pragma unroll
            for (int dt = 0; dt < 8; dt++) {
                bf16x8 vf = *reinterpret_cast<const bf16x8*>(Vt + (16 * dt + l15) * VS + 32 * kh + 8 * quad);
                o[0][dt] = __builtin_amdgcn_mfma_f32_16x16x32_bf16(pf0, vf, o[0][dt], 0, 0, 0);
                o[1][dt] = __builtin_amdgcn_mfma_f32_16x16x32_bf16(pf1, vf, o[1][dt], 0, 0, 0);
            }
        }
        __builtin_amdgcn_s_setprio(0);

        __syncthreads();                       // all reads of Ks/Vt done
        if (u + 1 < nunits) {
            write_unit();                      // regs -> LDS for next unit
            __syncthreads();
        }
    }

    // ---- epilogue: one-time l reduce across the 16-lane group, then write ----
    #pragma unroll
    for (int st = 1; st <= 8; st <<= 1)
        #pragma unroll
        for (int rt = 0; rt < 2; rt++)
            #pragma unroll
            for (int r = 0; r < 4; r++)
                l_i[rt][r] += __shfl_xor(l_i[rt][r], st, 64);

    #pragma unroll
    for (int rt = 0; rt < 2; rt++) {
        #pragma unroll
        for (int r = 0; r < 4; r++) {
            const int q = q0 + 32 * w + 16 * rt + 4 * quad + r;
            const float inv = 1.0f / l_i[rt][r];
            size_t base = ((size_t)b * T_SEQ + q) * 2048 + h * 128;
            #pragma unroll
            for (int dt = 0; dt < 8; dt++)
                obuf[base + 16 * dt + l15] = (__bf16)(o[rt][dt][r] * inv);
        }
    }
}

extern "C" void kernel_launch(void* const* d_in, const int* in_sizes, int n_in,
                              void* d_out, int out_size, void* d_ws, size_t ws_size,
                              hipStream_t stream)
{
    const float* x      = (const float*)d_in[0];
    const float* w_q    = (const float*)d_in[1];
    const float* w_dkv  = (const float*)d_in[2];
    const float* w_ukv  = (const float*)d_in[3];
    const float* w_o    = (const float*)d_in[4];
    const float* w_qrot = (const float*)d_in[5];
    const float* w_krot = (const float*)d_in[6];
    float* out = (float*)d_out;

    const size_t M = 4096;
    __bf16* ws   = (__bf16*)d_ws;
    __bf16* xb   = ws;                        // 4096x2048
    __bf16* wcat = xb + M * 2048;             // 3648x2048 = [w_q|w_qrot|w_krot|w_dkv]
    __bf16* wqb  = wcat;
    __bf16* wqrb = wcat + (size_t)2048 * 2048;
    __bf16* wkrb = wqrb + (size_t)1024 * 2048;
    __bf16* wdkb = wkrb + (size_t)64 * 2048;
    __bf16* wukb = wcat + (size_t)QSTR * 2048; // 4096x512
    __bf16* wob  = wukb + (size_t)4096 * 512;  // 2048x2048
    __bf16* qcat = wob  + (size_t)2048 * 2048; // 4096x3648 (q|qrot|krot|dkv)
    __bf16* ukv  = qcat + M * QSTR;            // 4096x4096
    __bf16* ao   = ukv  + M * 4096;            // 4096x2048
    __bf16* vtt  = ao   + M * 2048;            // 1024 tiles x 128x72 (~18.9MB)

    dim3 blk(256);
    cast_bf16<<<4096, blk, 0, stream>>>(x,      xb,   4096 * 2048);
    cast_bf16<<<2048, blk, 0, stream>>>(w_q,    wqb,  2048 * 2048);
    cast_bf16<<<1024, blk, 0, stream>>>(w_qrot, wqrb, 1024 * 2048);
    cast_bf16<<<64,   blk, 0, stream>>>(w_krot, wkrb, 64 * 2048);
    cast_bf16<<<512,  blk, 0, stream>>>(w_dkv,  wdkb, 512 * 2048);
    cast_bf16<<<1024, blk, 0, stream>>>(w_ukv,  wukb, 4096 * 512);
    cast_bf16<<<2048, blk, 0, stream>>>(w_o,    wob,  2048 * 2048);

    // one consolidated projection GEMM: [q|qrot|krot|dkv] = xb @ wcat^T
    gemm_bt_8ph<__bf16><<<dim3(15, 32), dim3(512), 0, stream>>>(
        xb, 2048, wcat, qcat, 4096, QSTR, 2048);
    // ukv = dkv @ w_ukv^T  (A = strided dkv slice of qcat)
    gemm_bt_8ph<__bf16><<<dim3(16, 32), dim3(512), 0, stream>>>(
        qcat + 3136, QSTR, wukb, ukv, 4096, 4096, 512);

    rope_ip<<<8192, blk, 0, stream>>>(qcat + 2048, 9, QSTR, 4096 * 512);
    rope_ip<<<512,  blk, 0, stream>>>(qcat + 3072, 5, QSTR, 4096 * 32);
    prep_v<<<dim3(32, 32), blk, 0, stream>>>(ukv, vtt);

    flash_mfma<<<dim3(16, 32), blk, 0, stream>>>(qcat, ukv, vtt, ao);

    gemm_bt_8ph<float><<<dim3(8, 32), dim3(512), 0, stream>>>(
        ao, 2048, wob, out, 4096, 2048, 2048);
}

// Round 5
// 394.635 us; speedup vs baseline: 1.7695x; 1.1563x over previous
//
#include <hip/hip_runtime.h>
#include <hip/hip_bf16.h>
#include <math.h>

#define T_SEQ 2048
#define QSTR  3648   // combined q|qrot|krot|dkv row stride

typedef __bf16 bf16x8 __attribute__((ext_vector_type(8)));
typedef float  f32x4  __attribute__((ext_vector_type(4)));
typedef float  f32x16 __attribute__((ext_vector_type(16)));
typedef unsigned int u32x4 __attribute__((ext_vector_type(4)));

#define GLOAD_LDS16(g, l) __builtin_amdgcn_global_load_lds( \
    (const __attribute__((address_space(1))) void*)(g),      \
    (__attribute__((address_space(3))) void*)(l), 16, 0, 0)

#define VMCNT(n) asm volatile("s_waitcnt vmcnt(" #n ")" ::: "memory")

static __device__ __forceinline__ unsigned cvtpk_bf16(float a, float b)
{
    unsigned r;
    asm("v_cvt_pk_bf16_f32 %0, %1, %2" : "=v"(r) : "v"(a), "v"(b));
    return r;
}

// ---------------- fp32 -> bf16 cast (8 el/thread) ----------------
__global__ __launch_bounds__(256) void cast_bf16(const float* __restrict__ src,
                                                 __bf16* __restrict__ dst, int n)
{
    int i = (blockIdx.x * 256 + threadIdx.x) * 8;
    if (i < n) {
        float4 a = *reinterpret_cast<const float4*>(src + i);
        float4 b = *reinterpret_cast<const float4*>(src + i + 4);
        bf16x8 f;
        f[0] = (__bf16)a.x; f[1] = (__bf16)a.y; f[2] = (__bf16)a.z; f[3] = (__bf16)a.w;
        f[4] = (__bf16)b.x; f[5] = (__bf16)b.y; f[6] = (__bf16)b.z; f[7] = (__bf16)b.w;
        *reinterpret_cast<bf16x8*>(dst + i) = f;
    }
}

// ---------------- in-place RoPE over 64-el head blocks (strided rows) -------
__global__ __launch_bounds__(256) void rope_ip(__bf16* buf, int shift, int stride,
                                               int total)
{
    int gid = blockIdx.x * 256 + threadIdx.x;
    if (gid >= total) return;
    int row = gid >> shift;
    int rem = gid & ((1 << shift) - 1);
    int hb = rem >> 5, j = rem & 31;
    int t = row & (T_SEQ - 1);
    const float L2B = 0.4152410118609203f;      // log2(10000)/32
    float freq = exp2f(-L2B * (float)j);
    float sn, cs;
    __sincosf((float)t * freq, &sn, &cs);
    size_t base = (size_t)row * stride + hb * 64 + j;
    float v1 = (float)buf[base], v2 = (float)buf[base + 32];
    buf[base]      = (__bf16)(v1 * cs - v2 * sn);
    buf[base + 32] = (__bf16)(v2 * cs + v1 * sn);
}

// ---------------- V pre-transpose: vtt[bh][u][dv(128)][k(64)] XOR-swizzled ---
// Element (dv,k) at dv*64 + ((k>>3 ^ (dv&7))<<3) + (k&7): flat (linear-dest)
// global_load_lds copy in flash lands it ready for conflict-reduced reads.
__global__ __launch_bounds__(256) void prep_v(const __bf16* __restrict__ ukv,
                                              __bf16* __restrict__ vtt)
{
    __shared__ __align__(16) __bf16 Ls[64 * 136];
    const int tid = threadIdx.x;
    const int u = blockIdx.x, bh = blockIdx.y;
    const int b = bh >> 4, h = bh & 15;
    const size_t base = (size_t)b * T_SEQ + u * 64;
    #pragma unroll
    for (int p = 0; p < 4; p++) {
        int c = tid + 256 * p;
        int k = c >> 4, dv8 = (c & 15) * 8;
        *reinterpret_cast<bf16x8*>(Ls + k * 136 + dv8) =
            *reinterpret_cast<const bf16x8*>(ukv + (base + k) * 4096 + h * 256 + 128 + dv8);
    }
    __syncthreads();
    #pragma unroll
    for (int p = 0; p < 4; p++) {
        int c = tid + 256 * p;
        int dv = c >> 3, kb = c & 7;
        bf16x8 f;
        #pragma unroll
        for (int i = 0; i < 8; i++) f[i] = Ls[(kb * 8 + i) * 136 + dv];
        *reinterpret_cast<bf16x8*>(vtt + (((size_t)bh * 32 + u) * 128 + dv) * 64
                                   + ((kb ^ (dv & 7)) << 3)) = f;
    }
}

// ---------------- 8-phase counted-vmcnt GEMM (T2+T3+T4+T5) ------------------
template <typename OutT>
__global__ __launch_bounds__(512) void gemm_bt_8ph(const __bf16* __restrict__ A,
                                                   int lda,
                                                   const __bf16* __restrict__ B,
                                                   OutT* __restrict__ C,
                                                   int M, int N, int K)
{
    __shared__ __align__(16) __bf16 S[2 * 24576];   // 96KB
    const int tid  = threadIdx.x;
    const int lane = tid & 63;
    const int w    = tid >> 6;
    const int l15  = lane & 15, quad = lane >> 4;
    const int wm = w >> 2, wn = w & 3;
    const int m0 = blockIdx.y * 128, n0 = blockIdx.x * 256;
    const int NT = K >> 6;

    f32x4 acc[4][4] = {};

    const int lrA = tid >> 3, segA = tid & 7;

    auto stageA = [&](int T1, int h) {
        int d = T1 & 1;
        int g = ((lrA >> 5) << 6) + h * 32 + (lrA & 31);
        GLOAD_LDS16(A + (size_t)(m0 + g) * lda + T1 * 64 + ((segA ^ (lrA & 7)) << 3),
                    S + d * 24576 + h * 4096 + tid * 8);
    };
    auto stageB = [&](int T1, int h) {
        int d = T1 & 1;
        #pragma unroll
        for (int i = 0; i < 2; i++) {
            int c = i * 512 + tid;
            int lr = c >> 3, seg = c & 7;
            int g = n0 + ((lr >> 5) << 6) + h * 32 + (lr & 31);
            if (g >= N) g = N - 1;
            GLOAD_LDS16(B + (size_t)g * K + T1 * 64 + ((seg ^ (lr & 7)) << 3),
                        S + d * 24576 + 8192 + h * 8192 + c * 8);
        }
    };

#define PHASE(d, mh, nh, STAGE, WAIT) do {                                     \
    const __bf16* Ah_ = S + (d) * 24576 + (mh) * 4096;                         \
    const __bf16* Bh_ = S + (d) * 24576 + 8192 + (nh) * 8192;                  \
    bf16x8 af[2][2], bfr[2][2];                                                \
    _Pragma("unroll")                                                          \
    for (int mr = 0; mr < 2; mr++) {                                           \
        int ar = wm * 32 + mr * 16 + l15;                                      \
        _Pragma("unroll")                                                      \
        for (int kk = 0; kk < 2; kk++)                                         \
            af[mr][kk] = *reinterpret_cast<const bf16x8*>(                     \
                Ah_ + ar * 64 + (((kk * 4 + quad) ^ (ar & 7)) << 3));          \
    }                                                                          \
    _Pragma("unroll")                                                          \
    for (int nr = 0; nr < 2; nr++) {                                           \
        int br = wn * 32 + nr * 16 + l15;                                      \
        _Pragma("unroll")                                                      \
        for (int kk = 0; kk < 2; kk++)                                         \
            bfr[nr][kk] = *reinterpret_cast<const bf16x8*>(                    \
                Bh_ + br * 64 + (((kk * 4 + quad) ^ (br & 7)) << 3));          \
    }                                                                          \
    STAGE;                                                                     \
    WAIT;                                                                      \
    __builtin_amdgcn_s_barrier();                                              \
    asm volatile("s_waitcnt lgkmcnt(0)" ::: "memory");                         \
    __builtin_amdgcn_sched_barrier(0);                                         \
    __builtin_amdgcn_s_setprio(1);                                             \
    _Pragma("unroll")                                                          \
    for (int mr = 0; mr < 2; mr++)                                             \
        _Pragma("unroll")                                                      \
        for (int nr = 0; nr < 2; nr++)                                         \
            _Pragma("unroll")                                                  \
            for (int kk = 0; kk < 2; kk++)                                     \
                acc[(mh) * 2 + mr][(nh) * 2 + nr] =                            \
                    __builtin_amdgcn_mfma_f32_16x16x32_bf16(                   \
                        af[mr][kk], bfr[nr][kk],                               \
                        acc[(mh) * 2 + mr][(nh) * 2 + nr], 0, 0, 0);           \
    __builtin_amdgcn_s_setprio(0);                                             \
} while (0)

    stageA(0, 0);
    stageB(0, 0);
    stageB(0, 1);
    stageA(0, 1);
    VMCNT(3);
    __builtin_amdgcn_s_barrier();

    for (int T = 0; T < NT - 1; T++) {
        const int d = T & 1;
        PHASE(d, 0, 0, stageA(T + 1, 0), VMCNT(2));
        PHASE(d, 0, 1, stageB(T + 1, 0), VMCNT(3));
        PHASE(d, 1, 0, stageB(T + 1, 1), (void)0);
        PHASE(d, 1, 1, stageA(T + 1, 1), VMCNT(3));
    }
    {
        const int d = (NT - 1) & 1;
        PHASE(d, 0, 0, (void)0, VMCNT(1));
        PHASE(d, 0, 1, (void)0, VMCNT(0));
        PHASE(d, 1, 0, (void)0, (void)0);
        PHASE(d, 1, 1, (void)0, (void)0);
    }
#undef PHASE

    #pragma unroll
    for (int ai = 0; ai < 4; ai++) {
        #pragma unroll
        for (int bj = 0; bj < 4; bj++) {
            int col = n0 + wn * 64 + bj * 16 + l15;
            if (col < N) {
                #pragma unroll
                for (int r = 0; r < 4; r++) {
                    size_t row = m0 + wm * 64 + ai * 16 + quad * 4 + r;
                    C[row * (size_t)N + col] = (OutT)acc[ai][bj][r];
                }
            }
        }
    }
}

// ---------------- MFMA flash attention v2: swapped 32x32, in-reg softmax ----
// qcat (4096,QSTR): [0,2048) q; [2048,3072) roped qrot; [3072,3136) roped krot.
// ukv (4096,4096): K-nope at h*256. vtt: pre-transposed+swizzled V tiles.
// Per block: 128 q-rows, 4 waves x 32 q (lane&31 = q-col, swapped operands).
// S^T = mfma_32x32x16(K, Q): softmax fully in-lane (m,l,alpha per-lane
// scalars); P packed to bf16 in regs (v_cvt_pk_bf16_f32 + one shfl_xor(32)
// half-exchange); O^T = mfma(V^T, P^T). No P LDS, no reg staging: all K/V
// staging via double-buffered global_load_lds with counted VMCNT(10) and raw
// s_barrier (never drained mid-loop). LDS exactly 80KB -> 2 blocks/CU.
__global__ __launch_bounds__(256, 2) void flash_mfma(
    const __bf16* __restrict__ qcat, const __bf16* __restrict__ ukv,
    const __bf16* __restrict__ vtt, __bf16* __restrict__ obuf)
{
    __shared__ __align__(16) __bf16 LDS[40960];  // KsN 2x8192 | KsR 2x4096 | Vt 2x8192

    const int tid  = threadIdx.x;
    const int w    = tid >> 6;
    const int lane = tid & 63;
    const int l31  = lane & 31;
    const int lh   = lane >> 5;
    const int l15  = lane & 15;
    const int quad = lane >> 4;
    const int gx = blockIdx.x, gy = blockIdx.y;
    int bh, qi;
    if (gy < 16) { bh = gy * 2;            qi = gx; }
    else         { bh = (gy - 16) * 2 + 1; qi = 15 - gx; }
    const int b = bh >> 4, h = bh & 15;
    const int q0 = qi * 128;
    const float SCALE = 0.07216878364870323f;   // 1/sqrt(192)
    const size_t urow = (size_t)b * T_SEQ;

    // ---- Q fragments (B-layout: lane = q-col l31, d = 16*dk + 8*lh + j) ----
    const int q = q0 + 32 * w + l31;
    bf16x8 qf[12];
    {
        const __bf16* qrow = qcat + (urow + q) * QSTR + h * 128;
        #pragma unroll
        for (int dk = 0; dk < 8; dk++)
            qf[dk] = *reinterpret_cast<const bf16x8*>(qrow + 16 * dk + 8 * lh);
        const __bf16* qrr = qcat + (urow + q) * QSTR + 2048 + h * 64;
        #pragma unroll
        for (int dk = 0; dk < 4; dk++)
            qf[8 + dk] = *reinterpret_cast<const bf16x8*>(qrr + 16 * dk + 8 * lh);
    }

    f32x16 o[4] = {};          // O^T accum: lane q-col, d rows in regs
    float m_i = -INFINITY, l_i = 0.f;

    const int nunits = 2 * qi + 2;

    auto stage = [&](int x) {           // 10 global_load_lds per thread
        const int d1 = x & 1;
        const size_t roff = urow + (size_t)64 * x;
        #pragma unroll
        for (int p = 0; p < 4; p++) {   // K-nope [64][128], swizzled source
            int c = tid + 256 * p;
            int row = c >> 4, seg = c & 15;
            GLOAD_LDS16(ukv + (roff + row) * 4096 + h * 256 + ((seg ^ (row & 7)) << 3),
                        LDS + d1 * 8192 + c * 8);
        }
        #pragma unroll
        for (int p = 0; p < 2; p++) {   // K-rope [64][64], swizzled source
            int c = tid + 256 * p;
            int row = c >> 3, seg = c & 7;
            GLOAD_LDS16(qcat + (roff + row) * QSTR + 3072 + ((seg ^ (row & 7)) << 3),
                        LDS + 16384 + d1 * 4096 + c * 8);
        }
        const __bf16* vsrc = vtt + ((size_t)bh * 32 + x) * 8192;
        #pragma unroll
        for (int p = 0; p < 4; p++) {   // V^T flat copy (pre-swizzled tile)
            int c = tid + 256 * p;
            GLOAD_LDS16(vsrc + c * 8, LDS + 24576 + d1 * 8192 + c * 8);
        }
    };

    stage(0);
    VMCNT(0);
    __builtin_amdgcn_s_barrier();

    for (int u = 0; u < nunits; u++) {
        // prefetch next tile into the other buffer (sealed by prev end-barrier)
        if (u + 1 < nunits) { stage(u + 1); VMCNT(10); }
        else                { VMCNT(0); }
        __builtin_amdgcn_s_barrier();
        __builtin_amdgcn_sched_barrier(0);

        const int d1 = u & 1;
        const __bf16* KN = LDS + d1 * 8192;
        const __bf16* KR = LDS + 16384 + d1 * 4096;
        const __bf16* VT = LDS + 24576 + d1 * 8192;
        const int key = l31 & 7;

        // ---- S^T = K Q^T: two 32x32 tiles over k ----
        f32x16 s2[2] = {};
        __builtin_amdgcn_s_setprio(1);
        #pragma unroll
        for (int t = 0; t < 2; t++) {
            const __bf16* kn = KN + (32 * t + l31) * 128;
            const __bf16* kr = KR + (32 * t + l31) * 64;
            #pragma unroll
            for (int dk = 0; dk < 8; dk++) {
                bf16x8 kf = *reinterpret_cast<const bf16x8*>(kn + (((2 * dk + lh) ^ key) << 3));
                s2[t] = __builtin_amdgcn_mfma_f32_32x32x16_bf16(kf, qf[dk], s2[t], 0, 0, 0);
            }
            #pragma unroll
            for (int dk = 0; dk < 4; dk++) {
                bf16x8 kf = *reinterpret_cast<const bf16x8*>(kr + (((2 * dk + lh) ^ key) << 3));
                s2[t] = __builtin_amdgcn_mfma_f32_32x32x16_bf16(kf, qf[8 + dk], s2[t], 0, 0, 0);
            }
        }
        __builtin_amdgcn_s_setprio(0);

        // ---- in-lane softmax over 32 values (k' = (g&3)+8*(g>>2)+4*lh) ----
        const int k0 = 64 * u;
        const bool domask = (u + 2 >= nunits);
        float rmax = -INFINITY;
        #pragma unroll
        for (int t = 0; t < 2; t++)
            #pragma unroll
            for (int g = 0; g < 16; g++) {
                float v = s2[t][g] * SCALE;
                if (domask) {
                    int kg = k0 + 32 * t + (g & 3) + 8 * (g >> 2) + 4 * lh;
                    if (kg > q) v = -INFINITY;
                }
                s2[t][g] = v;
                rmax = fmaxf(rmax, v);
            }
        rmax = fmaxf(rmax, __shfl_xor(rmax, 32, 64));
        const float mnew  = fmaxf(m_i, rmax);
        const float alpha = __expf(m_i - mnew);
        m_i = mnew;
        float part = 0.f;
        #pragma unroll
        for (int t = 0; t < 2; t++)
            #pragma unroll
            for (int g = 0; g < 16; g++) {
                float pv = __expf(s2[t][g] - mnew);
                s2[t][g] = pv;
                part += pv;
            }
        l_i = l_i * alpha + part;     // per-lane-half partial; summed in epilogue
        #pragma unroll
        for (int dt = 0; dt < 4; dt++) o[dt] *= alpha;

        // ---- pack P -> bf16 in regs + half-exchange; O^T += V^T P^T ----
        __builtin_amdgcn_s_setprio(1);
        #pragma unroll
        for (int t = 0; t < 2; t++) {
            unsigned Ap[4], Bp[4];
            #pragma unroll
            for (int g = 0; g < 4; g++) {
                Ap[g] = cvtpk_bf16(s2[t][4 * g],     s2[t][4 * g + 1]);
                Bp[g] = cvtpk_bf16(s2[t][4 * g + 2], s2[t][4 * g + 3]);
            }
            #pragma unroll
            for (int sub = 0; sub < 2; sub++) {
                unsigned xA = lh ? Ap[2 * sub] : Ap[2 * sub + 1];
                unsigned xB = lh ? Bp[2 * sub] : Bp[2 * sub + 1];
                unsigned rA = __shfl_xor(xA, 32, 64);
                unsigned rB = __shfl_xor(xB, 32, 64);
                u32x4 uv;
                uv[0] = lh ? rA : Ap[2 * sub];
                uv[1] = lh ? rB : Bp[2 * sub];
                uv[2] = lh ? Ap[2 * sub + 1] : rA;
                uv[3] = lh ? Bp[2 * sub + 1] : rB;
                bf16x8 pf = __builtin_bit_cast(bf16x8, uv);
                const int s = 2 * t + sub;
                #pragma unroll
                for (int dt = 0; dt < 4; dt++) {
                    bf16x8 vf = *reinterpret_cast<const bf16x8*>(
                        VT + (32 * dt + l31) * 64 + (((2 * s + lh) ^ key) << 3));
                    o[dt] = __builtin_amdgcn_mfma_f32_32x32x16_bf16(vf, pf, o[dt], 0, 0, 0);
                }
            }
        }
        __builtin_amdgcn_s_setprio(0);

        __builtin_amdgcn_sched_barrier(0);
        __builtin_amdgcn_s_barrier();      // seal reads of buf[u&1]
    }

    // ---- epilogue: transpose O^T through LDS, coalesced bf16 stores ----
    const float linv = 1.0f / (l_i + __shfl_xor(l_i, 32, 64));
    float* Os = reinterpret_cast<float*>(LDS);     // [128 q][132 d] = 67.5KB
    #pragma unroll
    for (int dt = 0; dt < 4; dt++)
        #pragma unroll
        for (int g = 0; g < 16; g++) {
            int d = 32 * dt + (g & 3) + 8 * (g >> 2) + 4 * lh;
            Os[(32 * w + l31) * 132 + d] = o[dt][g] * linv;
        }
    asm volatile("s_waitcnt lgkmcnt(0)" ::: "memory");
    __builtin_amdgcn_sched_barrier(0);
    // rows [32w,32w+32) written and read by wave w only: no cross-wave barrier
    #pragma unroll
    for (int p = 0; p < 8; p++) {
        int row = 32 * w + 4 * p + quad;
        float4 a  = *reinterpret_cast<const float4*>(Os + row * 132 + 8 * l15);
        float4 c2 = *reinterpret_cast<const float4*>(Os + row * 132 + 8 * l15 + 4);
        bf16x8 f;
        f[0] = (__bf16)a.x;  f[1] = (__bf16)a.y;  f[2] = (__bf16)a.z;  f[3] = (__bf16)a.w;
        f[4] = (__bf16)c2.x; f[5] = (__bf16)c2.y; f[6] = (__bf16)c2.z; f[7] = (__bf16)c2.w;
        *reinterpret_cast<bf16x8*>(obuf + (urow + q0 + row) * 2048 + h * 128 + 8 * l15) = f;
    }
}

extern "C" void kernel_launch(void* const* d_in, const int* in_sizes, int n_in,
                              void* d_out, int out_size, void* d_ws, size_t ws_size,
                              hipStream_t stream)
{
    const float* x      = (const float*)d_in[0];
    const float* w_q    = (const float*)d_in[1];
    const float* w_dkv  = (const float*)d_in[2];
    const float* w_ukv  = (const float*)d_in[3];
    const float* w_o    = (const float*)d_in[4];
    const float* w_qrot = (const float*)d_in[5];
    const float* w_krot = (const float*)d_in[6];
    float* out = (float*)d_out;

    const size_t M = 4096;
    __bf16* ws   = (__bf16*)d_ws;
    __bf16* xb   = ws;                        // 4096x2048
    __bf16* wcat = xb + M * 2048;             // 3648x2048 = [w_q|w_qrot|w_krot|w_dkv]
    __bf16* wqb  = wcat;
    __bf16* wqrb = wcat + (size_t)2048 * 2048;
    __bf16* wkrb = wqrb + (size_t)1024 * 2048;
    __bf16* wdkb = wkrb + (size_t)64 * 2048;
    __bf16* wukb = wcat + (size_t)QSTR * 2048; // 4096x512
    __bf16* wob  = wukb + (size_t)4096 * 512;  // 2048x2048
    __bf16* qcat = wob  + (size_t)2048 * 2048; // 4096x3648 (q|qrot|krot|dkv)
    __bf16* ukv  = qcat + M * QSTR;            // 4096x4096
    __bf16* ao   = ukv  + M * 4096;            // 4096x2048
    __bf16* vtt  = ao   + M * 2048;            // 1024 tiles x 128x64 (~16.8MB)

    dim3 blk(256);
    cast_bf16<<<4096, blk, 0, stream>>>(x,      xb,   4096 * 2048);
    cast_bf16<<<2048, blk, 0, stream>>>(w_q,    wqb,  2048 * 2048);
    cast_bf16<<<1024, blk, 0, stream>>>(w_qrot, wqrb, 1024 * 2048);
    cast_bf16<<<64,   blk, 0, stream>>>(w_krot, wkrb, 64 * 2048);
    cast_bf16<<<512,  blk, 0, stream>>>(w_dkv,  wdkb, 512 * 2048);
    cast_bf16<<<1024, blk, 0, stream>>>(w_ukv,  wukb, 4096 * 512);
    cast_bf16<<<2048, blk, 0, stream>>>(w_o,    wob,  2048 * 2048);

    // one consolidated projection GEMM: [q|qrot|krot|dkv] = xb @ wcat^T
    gemm_bt_8ph<__bf16><<<dim3(15, 32), dim3(512), 0, stream>>>(
        xb, 2048, wcat, qcat, 4096, QSTR, 2048);
    // ukv = dkv @ w_ukv^T  (A = strided dkv slice of qcat)
    gemm_bt_8ph<__bf16><<<dim3(16, 32), dim3(512), 0, stream>>>(
        qcat + 3136, QSTR, wukb, ukv, 4096, 4096, 512);

    rope_ip<<<8192, blk, 0, stream>>>(qcat + 2048, 9, QSTR, 4096 * 512);
    rope_ip<<<512,  blk, 0, stream>>>(qcat + 3072, 5, QSTR, 4096 * 32);
    prep_v<<<dim3(32, 32), blk, 0, stream>>>(ukv, vtt);

    flash_mfma<<<dim3(16, 32), blk, 0, stream>>>(qcat, ukv, vtt, ao);

    gemm_bt_8ph<float><<<dim3(8, 32), dim3(512), 0, stream>>>(
        ao, 2048, wob, out, 4096, 2048, 2048);
}

// Round 6
// 370.031 us; speedup vs baseline: 1.8872x; 1.0665x over previous
//
#include <hip/hip_runtime.h>
#include <hip/hip_bf16.h>
#include <math.h>

#define T_SEQ 2048
#define QSTR  3648   // combined q|qrot|krot|dkv row stride

typedef __bf16 bf16x8 __attribute__((ext_vector_type(8)));
typedef float  f32x4  __attribute__((ext_vector_type(4)));
typedef float  f32x16 __attribute__((ext_vector_type(16)));
typedef unsigned int u32x4 __attribute__((ext_vector_type(4)));

#define GLOAD_LDS16(g, l) __builtin_amdgcn_global_load_lds( \
    (const __attribute__((address_space(1))) void*)(g),      \
    (__attribute__((address_space(3))) void*)(l), 16, 0, 0)

#define VMCNT(n) asm volatile("s_waitcnt vmcnt(" #n ")" ::: "memory")

static __device__ __forceinline__ unsigned cvtpk_bf16(float a, float b)
{
    unsigned r;
    asm("v_cvt_pk_bf16_f32 %0, %1, %2" : "=v"(r) : "v"(a), "v"(b));
    return r;
}

// ---------------- fused fp32 -> bf16 cast for all 7 buffers ----------------
struct CastArgs {
    const float* s[7];
    __bf16*      d[7];
    unsigned     cum[8];    // cumulative block counts (2048 elements per block)
};

__global__ __launch_bounds__(256) void cast_all(CastArgs a)
{
    const unsigned blk = blockIdx.x;
    int idx = 0;
    #pragma unroll
    for (int i = 1; i < 7; i++) if (blk >= a.cum[i]) idx = i;
    const unsigned local = blk - a.cum[idx];
    const float* src = a.s[idx];
    __bf16* dst = a.d[idx];
    const int i = (int)(local * 256 + threadIdx.x) * 8;
    float4 va = *reinterpret_cast<const float4*>(src + i);
    float4 vb = *reinterpret_cast<const float4*>(src + i + 4);
    bf16x8 f;
    f[0] = (__bf16)va.x; f[1] = (__bf16)va.y; f[2] = (__bf16)va.z; f[3] = (__bf16)va.w;
    f[4] = (__bf16)vb.x; f[5] = (__bf16)vb.y; f[6] = (__bf16)vb.z; f[7] = (__bf16)vb.w;
    *reinterpret_cast<bf16x8*>(dst + i) = f;
}

// ---------------- in-place RoPE over 64-el head blocks (strided rows) -------
__global__ __launch_bounds__(256) void rope_ip(__bf16* buf, int shift, int stride,
                                               int total)
{
    int gid = blockIdx.x * 256 + threadIdx.x;
    if (gid >= total) return;
    int row = gid >> shift;
    int rem = gid & ((1 << shift) - 1);
    int hb = rem >> 5, j = rem & 31;
    int t = row & (T_SEQ - 1);
    const float L2B = 0.4152410118609203f;      // log2(10000)/32
    float freq = exp2f(-L2B * (float)j);
    float sn, cs;
    __sincosf((float)t * freq, &sn, &cs);
    size_t base = (size_t)row * stride + hb * 64 + j;
    float v1 = (float)buf[base], v2 = (float)buf[base + 32];
    buf[base]      = (__bf16)(v1 * cs - v2 * sn);
    buf[base + 32] = (__bf16)(v2 * cs + v1 * sn);
}

// ---------------- V pre-transpose: vtt[bh][u][dv(128)][k(64)] XOR-swizzled ---
__global__ __launch_bounds__(256) void prep_v(const __bf16* __restrict__ ukv,
                                              __bf16* __restrict__ vtt)
{
    __shared__ __align__(16) __bf16 Ls[64 * 136];
    const int tid = threadIdx.x;
    const int u = blockIdx.x, bh = blockIdx.y;
    const int b = bh >> 4, h = bh & 15;
    const size_t base = (size_t)b * T_SEQ + u * 64;
    #pragma unroll
    for (int p = 0; p < 4; p++) {
        int c = tid + 256 * p;
        int k = c >> 4, dv8 = (c & 15) * 8;
        *reinterpret_cast<bf16x8*>(Ls + k * 136 + dv8) =
            *reinterpret_cast<const bf16x8*>(ukv + (base + k) * 4096 + h * 256 + 128 + dv8);
    }
    __syncthreads();
    #pragma unroll
    for (int p = 0; p < 4; p++) {
        int c = tid + 256 * p;
        int dv = c >> 3, kb = c & 7;
        bf16x8 f;
        #pragma unroll
        for (int i = 0; i < 8; i++) f[i] = Ls[(kb * 8 + i) * 136 + dv];
        *reinterpret_cast<bf16x8*>(vtt + (((size_t)bh * 32 + u) * 128 + dv) * 64
                                   + ((kb ^ (dv & 7)) << 3)) = f;
    }
}

// ---------------- 256x256 snake-phase counted-vmcnt GEMM --------------------
// BM=BN=256 BK=64, 512 thr, 8 waves (2M x 4N), per-wave 128x64 output.
// LDS 128KB: 2 dbuf x {A 256x64 (row-bit6 halves), B 256x64 (row-bit5 halves)}.
// Snake phase order (0,0)(0,1)(1,1)(1,0): each phase reloads ONE operand's
// fragments (8 or 4 ds_read_b128) against 16 MFMA. Staging order per tile:
// Ah0,Bh0,Bh1,Ah1 (2 gload_lds each); uniform VMCNT(4) drains exactly the
// half the NEXT phase reads; vmcnt never 0 mid-loop.
template <typename OutT>
__global__ __launch_bounds__(512, 2) void gemm_bt_256(const __bf16* __restrict__ A,
                                                      int lda,
                                                      const __bf16* __restrict__ B,
                                                      OutT* __restrict__ C,
                                                      int M, int N, int K)
{
    __shared__ __align__(16) __bf16 S[2 * 32768];   // 128KB
    const int tid  = threadIdx.x;
    const int lane = tid & 63;
    const int w    = tid >> 6;
    const int l15  = lane & 15, quad = lane >> 4;
    const int wm = w >> 2, wn = w & 3;
    const int m0 = blockIdx.y * 256, n0 = blockIdx.x * 256;
    const int NT = K >> 6;

    f32x4 acc[8][4] = {};
    bf16x8 af[4][2], bfr[2][2];

    auto stageA = [&](int T1, int h) {
        int d = T1 & 1;
        #pragma unroll
        for (int i = 0; i < 2; i++) {
            int c = i * 512 + tid;
            int lr = c >> 3, seg = c & 7;
            int g = ((lr >> 6) << 7) + h * 64 + (lr & 63);
            GLOAD_LDS16(A + (size_t)(m0 + g) * lda + T1 * 64 + ((seg ^ (lr & 7)) << 3),
                        S + d * 32768 + h * 8192 + c * 8);
        }
    };
    auto stageB = [&](int T1, int h) {
        int d = T1 & 1;
        #pragma unroll
        for (int i = 0; i < 2; i++) {
            int c = i * 512 + tid;
            int lr = c >> 3, seg = c & 7;
            int g = n0 + ((lr >> 5) << 6) + h * 32 + (lr & 31);
            if (g >= N) g = N - 1;
            GLOAD_LDS16(B + (size_t)g * K + T1 * 64 + ((seg ^ (lr & 7)) << 3),
                        S + d * 32768 + 16384 + h * 8192 + c * 8);
        }
    };

#define LOADA(d, mh) do {                                                      \
    const __bf16* Ah_ = S + (d) * 32768 + (mh) * 8192;                         \
    _Pragma("unroll")                                                          \
    for (int mi = 0; mi < 4; mi++) {                                           \
        int lr = wm * 64 + mi * 16 + l15;                                      \
        _Pragma("unroll")                                                      \
        for (int kk = 0; kk < 2; kk++)                                         \
            af[mi][kk] = *reinterpret_cast<const bf16x8*>(                     \
                Ah_ + lr * 64 + (((kk * 4 + quad) ^ (lr & 7)) << 3));          \
    }                                                                          \
} while (0)

#define LOADB(d, nh) do {                                                      \
    const __bf16* Bh_ = S + (d) * 32768 + 16384 + (nh) * 8192;                 \
    _Pragma("unroll")                                                          \
    for (int ni = 0; ni < 2; ni++) {                                           \
        int lr = wn * 32 + ni * 16 + l15;                                      \
        _Pragma("unroll")                                                      \
        for (int kk = 0; kk < 2; kk++)                                         \
            bfr[ni][kk] = *reinterpret_cast<const bf16x8*>(                    \
                Bh_ + lr * 64 + (((kk * 4 + quad) ^ (lr & 7)) << 3));          \
    }                                                                          \
} while (0)

#define SEAL() do {                                                            \
    __builtin_amdgcn_s_barrier();                                              \
    asm volatile("s_waitcnt lgkmcnt(0)" ::: "memory");                         \
    __builtin_amdgcn_sched_barrier(0);                                         \
} while (0)

#define MMA(mh, nh) do {                                                       \
    __builtin_amdgcn_s_setprio(1);                                             \
    _Pragma("unroll")                                                          \
    for (int mi = 0; mi < 4; mi++)                                             \
        _Pragma("unroll")                                                      \
        for (int ni = 0; ni < 2; ni++)                                         \
            _Pragma("unroll")                                                  \
            for (int kk = 0; kk < 2; kk++)                                     \
                acc[(mh) * 4 + mi][(nh) * 2 + ni] =                            \
                    __builtin_amdgcn_mfma_f32_16x16x32_bf16(                   \
                        af[mi][kk], bfr[ni][kk],                               \
                        acc[(mh) * 4 + mi][(nh) * 2 + ni], 0, 0, 0);           \
    __builtin_amdgcn_s_setprio(0);                                             \
} while (0)

    // prologue: stage tile 0 (8 loads); first 4 (Ah0,Bh0) must land
    stageA(0, 0); stageB(0, 0); stageB(0, 1); stageA(0, 1);
    VMCNT(4);
    __builtin_amdgcn_s_barrier();

    for (int T = 0; T < NT - 1; T++) {
        const int d = T & 1;
        LOADA(d, 0); LOADB(d, 0); stageA(T + 1, 0); VMCNT(4); SEAL(); MMA(0, 0);
        LOADB(d, 1);              stageB(T + 1, 0); VMCNT(4); SEAL(); MMA(0, 1);
        LOADA(d, 1);              stageB(T + 1, 1);           SEAL(); MMA(1, 1);
        LOADB(d, 0);              stageA(T + 1, 1); VMCNT(4); SEAL(); MMA(1, 0);
    }
    {   // tail tile: no staging; drain progressively
        const int d = (NT - 1) & 1;
        LOADA(d, 0); LOADB(d, 0); VMCNT(2); SEAL(); MMA(0, 0);
        LOADB(d, 1);              VMCNT(0); SEAL(); MMA(0, 1);
        LOADA(d, 1);                        SEAL(); MMA(1, 1);
        LOADB(d, 0);                        SEAL(); MMA(1, 0);
    }
#undef LOADA
#undef LOADB
#undef SEAL
#undef MMA

    #pragma unroll
    for (int ai = 0; ai < 8; ai++) {
        #pragma unroll
        for (int bj = 0; bj < 4; bj++) {
            int col = n0 + wn * 64 + bj * 16 + l15;
            if (col < N) {
                #pragma unroll
                for (int r = 0; r < 4; r++) {
                    size_t row = m0 + wm * 128 + ai * 16 + quad * 4 + r;
                    C[row * (size_t)N + col] = (OutT)acc[ai][bj][r];
                }
            }
        }
    }
}

// ---------------- 8-phase counted-vmcnt GEMM, BM=128 (kept for out GEMM) ----
template <typename OutT>
__global__ __launch_bounds__(512) void gemm_bt_8ph(const __bf16* __restrict__ A,
                                                   int lda,
                                                   const __bf16* __restrict__ B,
                                                   OutT* __restrict__ C,
                                                   int M, int N, int K)
{
    __shared__ __align__(16) __bf16 S[2 * 24576];   // 96KB
    const int tid  = threadIdx.x;
    const int lane = tid & 63;
    const int w    = tid >> 6;
    const int l15  = lane & 15, quad = lane >> 4;
    const int wm = w >> 2, wn = w & 3;
    const int m0 = blockIdx.y * 128, n0 = blockIdx.x * 256;
    const int NT = K >> 6;

    f32x4 acc[4][4] = {};

    const int lrA = tid >> 3, segA = tid & 7;

    auto stageA = [&](int T1, int h) {
        int d = T1 & 1;
        int g = ((lrA >> 5) << 6) + h * 32 + (lrA & 31);
        GLOAD_LDS16(A + (size_t)(m0 + g) * lda + T1 * 64 + ((segA ^ (lrA & 7)) << 3),
                    S + d * 24576 + h * 4096 + tid * 8);
    };
    auto stageB = [&](int T1, int h) {
        int d = T1 & 1;
        #pragma unroll
        for (int i = 0; i < 2; i++) {
            int c = i * 512 + tid;
            int lr = c >> 3, seg = c & 7;
            int g = n0 + ((lr >> 5) << 6) + h * 32 + (lr & 31);
            if (g >= N) g = N - 1;
            GLOAD_LDS16(B + (size_t)g * K + T1 * 64 + ((seg ^ (lr & 7)) << 3),
                        S + d * 24576 + 8192 + h * 8192 + c * 8);
        }
    };

#define PHASE(d, mh, nh, STAGE, WAIT) do {                                     \
    const __bf16* Ah_ = S + (d) * 24576 + (mh) * 4096;                         \
    const __bf16* Bh_ = S + (d) * 24576 + 8192 + (nh) * 8192;                  \
    bf16x8 af[2][2], bfr[2][2];                                                \
    _Pragma("unroll")                                                          \
    for (int mr = 0; mr < 2; mr++) {                                           \
        int ar = wm * 32 + mr * 16 + l15;                                      \
        _Pragma("unroll")                                                      \
        for (int kk = 0; kk < 2; kk++)                                         \
            af[mr][kk] = *reinterpret_cast<const bf16x8*>(                     \
                Ah_ + ar * 64 + (((kk * 4 + quad) ^ (ar & 7)) << 3));          \
    }                                                                          \
    _Pragma("unroll")                                                          \
    for (int nr = 0; nr < 2; nr++) {                                           \
        int br = wn * 32 + nr * 16 + l15;                                      \
        _Pragma("unroll")                                                      \
        for (int kk = 0; kk < 2; kk++)                                         \
            bfr[nr][kk] = *reinterpret_cast<const bf16x8*>(                    \
                Bh_ + br * 64 + (((kk * 4 + quad) ^ (br & 7)) << 3));          \
    }                                                                          \
    STAGE;                                                                     \
    WAIT;                                                                      \
    __builtin_amdgcn_s_barrier();                                              \
    asm volatile("s_waitcnt lgkmcnt(0)" ::: "memory");                         \
    __builtin_amdgcn_sched_barrier(0);                                         \
    __builtin_amdgcn_s_setprio(1);                                             \
    _Pragma("unroll")                                                          \
    for (int mr = 0; mr < 2; mr++)                                             \
        _Pragma("unroll")                                                      \
        for (int nr = 0; nr < 2; nr++)                                         \
            _Pragma("unroll")                                                  \
            for (int kk = 0; kk < 2; kk++)                                     \
                acc[(mh) * 2 + mr][(nh) * 2 + nr] =                            \
                    __builtin_amdgcn_mfma_f32_16x16x32_bf16(                   \
                        af[mr][kk], bfr[nr][kk],                               \
                        acc[(mh) * 2 + mr][(nh) * 2 + nr], 0, 0, 0);           \
    __builtin_amdgcn_s_setprio(0);                                             \
} while (0)

    stageA(0, 0);
    stageB(0, 0);
    stageB(0, 1);
    stageA(0, 1);
    VMCNT(3);
    __builtin_amdgcn_s_barrier();

    for (int T = 0; T < NT - 1; T++) {
        const int d = T & 1;
        PHASE(d, 0, 0, stageA(T + 1, 0), VMCNT(2));
        PHASE(d, 0, 1, stageB(T + 1, 0), VMCNT(3));
        PHASE(d, 1, 0, stageB(T + 1, 1), (void)0);
        PHASE(d, 1, 1, stageA(T + 1, 1), VMCNT(3));
    }
    {
        const int d = (NT - 1) & 1;
        PHASE(d, 0, 0, (void)0, VMCNT(1));
        PHASE(d, 0, 1, (void)0, VMCNT(0));
        PHASE(d, 1, 0, (void)0, (void)0);
        PHASE(d, 1, 1, (void)0, (void)0);
    }
#undef PHASE

    #pragma unroll
    for (int ai = 0; ai < 4; ai++) {
        #pragma unroll
        for (int bj = 0; bj < 4; bj++) {
            int col = n0 + wn * 64 + bj * 16 + l15;
            if (col < N) {
                #pragma unroll
                for (int r = 0; r < 4; r++) {
                    size_t row = m0 + wm * 64 + ai * 16 + quad * 4 + r;
                    C[row * (size_t)N + col] = (OutT)acc[ai][bj][r];
                }
            }
        }
    }
}

// ---------------- MFMA flash attention v2: swapped 32x32, in-reg softmax ----
__global__ __launch_bounds__(256, 2) void flash_mfma(
    const __bf16* __restrict__ qcat, const __bf16* __restrict__ ukv,
    const __bf16* __restrict__ vtt, __bf16* __restrict__ obuf)
{
    __shared__ __align__(16) __bf16 LDS[40960];  // KsN 2x8192 | KsR 2x4096 | Vt 2x8192

    const int tid  = threadIdx.x;
    const int w    = tid >> 6;
    const int lane = tid & 63;
    const int l31  = lane & 31;
    const int lh   = lane >> 5;
    const int l15  = lane & 15;
    const int quad = lane >> 4;
    const int gx = blockIdx.x, gy = blockIdx.y;
    int bh, qi;
    if (gy < 16) { bh = gy * 2;            qi = gx; }
    else         { bh = (gy - 16) * 2 + 1; qi = 15 - gx; }
    const int b = bh >> 4, h = bh & 15;
    const int q0 = qi * 128;
    const float SCALE = 0.07216878364870323f;   // 1/sqrt(192)
    const size_t urow = (size_t)b * T_SEQ;

    const int q = q0 + 32 * w + l31;
    bf16x8 qf[12];
    {
        const __bf16* qrow = qcat + (urow + q) * QSTR + h * 128;
        #pragma unroll
        for (int dk = 0; dk < 8; dk++)
            qf[dk] = *reinterpret_cast<const bf16x8*>(qrow + 16 * dk + 8 * lh);
        const __bf16* qrr = qcat + (urow + q) * QSTR + 2048 + h * 64;
        #pragma unroll
        for (int dk = 0; dk < 4; dk++)
            qf[8 + dk] = *reinterpret_cast<const bf16x8*>(qrr + 16 * dk + 8 * lh);
    }

    f32x16 o[4] = {};
    float m_i = -INFINITY, l_i = 0.f;

    const int nunits = 2 * qi + 2;

    auto stage = [&](int x) {           // 10 global_load_lds per thread
        const int d1 = x & 1;
        const size_t roff = urow + (size_t)64 * x;
        #pragma unroll
        for (int p = 0; p < 4; p++) {
            int c = tid + 256 * p;
            int row = c >> 4, seg = c & 15;
            GLOAD_LDS16(ukv + (roff + row) * 4096 + h * 256 + ((seg ^ (row & 7)) << 3),
                        LDS + d1 * 8192 + c * 8);
        }
        #pragma unroll
        for (int p = 0; p < 2; p++) {
            int c = tid + 256 * p;
            int row = c >> 3, seg = c & 7;
            GLOAD_LDS16(qcat + (roff + row) * QSTR + 3072 + ((seg ^ (row & 7)) << 3),
                        LDS + 16384 + d1 * 4096 + c * 8);
        }
        const __bf16* vsrc = vtt + ((size_t)bh * 32 + x) * 8192;
        #pragma unroll
        for (int p = 0; p < 4; p++) {
            int c = tid + 256 * p;
            GLOAD_LDS16(vsrc + c * 8, LDS + 24576 + d1 * 8192 + c * 8);
        }
    };

    stage(0);
    VMCNT(0);
    __builtin_amdgcn_s_barrier();

    for (int u = 0; u < nunits; u++) {
        if (u + 1 < nunits) { stage(u + 1); VMCNT(10); }
        else                { VMCNT(0); }
        __builtin_amdgcn_s_barrier();
        __builtin_amdgcn_sched_barrier(0);

        const int d1 = u & 1;
        const __bf16* KN = LDS + d1 * 8192;
        const __bf16* KR = LDS + 16384 + d1 * 4096;
        const __bf16* VT = LDS + 24576 + d1 * 8192;
        const int key = l31 & 7;

        f32x16 s2[2] = {};
        __builtin_amdgcn_s_setprio(1);
        #pragma unroll
        for (int t = 0; t < 2; t++) {
            const __bf16* kn = KN + (32 * t + l31) * 128;
            const __bf16* kr = KR + (32 * t + l31) * 64;
            #pragma unroll
            for (int dk = 0; dk < 8; dk++) {
                bf16x8 kf = *reinterpret_cast<const bf16x8*>(kn + (((2 * dk + lh) ^ key) << 3));
                s2[t] = __builtin_amdgcn_mfma_f32_32x32x16_bf16(kf, qf[dk], s2[t], 0, 0, 0);
            }
            #pragma unroll
            for (int dk = 0; dk < 4; dk++) {
                bf16x8 kf = *reinterpret_cast<const bf16x8*>(kr + (((2 * dk + lh) ^ key) << 3));
                s2[t] = __builtin_amdgcn_mfma_f32_32x32x16_bf16(kf, qf[8 + dk], s2[t], 0, 0, 0);
            }
        }
        __builtin_amdgcn_s_setprio(0);

        const int k0 = 64 * u;
        const bool domask = (u + 2 >= nunits);
        float rmax = -INFINITY;
        #pragma unroll
        for (int t = 0; t < 2; t++)
            #pragma unroll
            for (int g = 0; g < 16; g++) {
                float v = s2[t][g] * SCALE;
                if (domask) {
                    int kg = k0 + 32 * t + (g & 3) + 8 * (g >> 2) + 4 * lh;
                    if (kg > q) v = -INFINITY;
                }
                s2[t][g] = v;
                rmax = fmaxf(rmax, v);
            }
        rmax = fmaxf(rmax, __shfl_xor(rmax, 32, 64));
        const float mnew  = fmaxf(m_i, rmax);
        const float alpha = __expf(m_i - mnew);
        m_i = mnew;
        float part = 0.f;
        #pragma unroll
        for (int t = 0; t < 2; t++)
            #pragma unroll
            for (int g = 0; g < 16; g++) {
                float pv = __expf(s2[t][g] - mnew);
                s2[t][g] = pv;
                part += pv;
            }
        l_i = l_i * alpha + part;
        #pragma unroll
        for (int dt = 0; dt < 4; dt++) o[dt] *= alpha;

        __builtin_amdgcn_s_setprio(1);
        #pragma unroll
        for (int t = 0; t < 2; t++) {
            unsigned Ap[4], Bp[4];
            #pragma unroll
            for (int g = 0; g < 4; g++) {
                Ap[g] = cvtpk_bf16(s2[t][4 * g],     s2[t][4 * g + 1]);
                Bp[g] = cvtpk_bf16(s2[t][4 * g + 2], s2[t][4 * g + 3]);
            }
            #pragma unroll
            for (int sub = 0; sub < 2; sub++) {
                unsigned xA = lh ? Ap[2 * sub] : Ap[2 * sub + 1];
                unsigned xB = lh ? Bp[2 * sub] : Bp[2 * sub + 1];
                unsigned rA = __shfl_xor(xA, 32, 64);
                unsigned rB = __shfl_xor(xB, 32, 64);
                u32x4 uv;
                uv[0] = lh ? rA : Ap[2 * sub];
                uv[1] = lh ? rB : Bp[2 * sub];
                uv[2] = lh ? Ap[2 * sub + 1] : rA;
                uv[3] = lh ? Bp[2 * sub + 1] : rB;
                bf16x8 pf = __builtin_bit_cast(bf16x8, uv);
                const int s = 2 * t + sub;
                #pragma unroll
                for (int dt = 0; dt < 4; dt++) {
                    bf16x8 vf = *reinterpret_cast<const bf16x8*>(
                        VT + (32 * dt + l31) * 64 + (((2 * s + lh) ^ key) << 3));
                    o[dt] = __builtin_amdgcn_mfma_f32_32x32x16_bf16(vf, pf, o[dt], 0, 0, 0);
                }
            }
        }
        __builtin_amdgcn_s_setprio(0);

        __builtin_amdgcn_sched_barrier(0);
        __builtin_amdgcn_s_barrier();
    }

    const float linv = 1.0f / (l_i + __shfl_xor(l_i, 32, 64));
    float* Os = reinterpret_cast<float*>(LDS);     // [128 q][132 d]
    #pragma unroll
    for (int dt = 0; dt < 4; dt++)
        #pragma unroll
        for (int g = 0; g < 16; g++) {
            int d = 32 * dt + (g & 3) + 8 * (g >> 2) + 4 * lh;
            Os[(32 * w + l31) * 132 + d] = o[dt][g] * linv;
        }
    asm volatile("s_waitcnt lgkmcnt(0)" ::: "memory");
    __builtin_amdgcn_sched_barrier(0);
    #pragma unroll
    for (int p = 0; p < 8; p++) {
        int row = 32 * w + 4 * p + quad;
        float4 a  = *reinterpret_cast<const float4*>(Os + row * 132 + 8 * l15);
        float4 c2 = *reinterpret_cast<const float4*>(Os + row * 132 + 8 * l15 + 4);
        bf16x8 f;
        f[0] = (__bf16)a.x;  f[1] = (__bf16)a.y;  f[2] = (__bf16)a.z;  f[3] = (__bf16)a.w;
        f[4] = (__bf16)c2.x; f[5] = (__bf16)c2.y; f[6] = (__bf16)c2.z; f[7] = (__bf16)c2.w;
        *reinterpret_cast<bf16x8*>(obuf + (urow + q0 + row) * 2048 + h * 128 + 8 * l15) = f;
    }
}

extern "C" void kernel_launch(void* const* d_in, const int* in_sizes, int n_in,
                              void* d_out, int out_size, void* d_ws, size_t ws_size,
                              hipStream_t stream)
{
    const float* x      = (const float*)d_in[0];
    const float* w_q    = (const float*)d_in[1];
    const float* w_dkv  = (const float*)d_in[2];
    const float* w_ukv  = (const float*)d_in[3];
    const float* w_o    = (const float*)d_in[4];
    const float* w_qrot = (const float*)d_in[5];
    const float* w_krot = (const float*)d_in[6];
    float* out = (float*)d_out;

    const size_t M = 4096;
    __bf16* ws   = (__bf16*)d_ws;
    __bf16* xb   = ws;                        // 4096x2048
    __bf16* wcat = xb + M * 2048;             // 3648x2048 = [w_q|w_qrot|w_krot|w_dkv]
    __bf16* wqb  = wcat;
    __bf16* wqrb = wcat + (size_t)2048 * 2048;
    __bf16* wkrb = wqrb + (size_t)1024 * 2048;
    __bf16* wdkb = wkrb + (size_t)64 * 2048;
    __bf16* wukb = wcat + (size_t)QSTR * 2048; // 4096x512
    __bf16* wob  = wukb + (size_t)4096 * 512;  // 2048x2048
    __bf16* qcat = wob  + (size_t)2048 * 2048; // 4096x3648 (q|qrot|krot|dkv)
    __bf16* ukv  = qcat + M * QSTR;            // 4096x4096
    __bf16* ao   = ukv  + M * 4096;            // 4096x2048
    __bf16* vtt  = ao   + M * 2048;            // 1024 tiles x 128x64 (~16.8MB)

    dim3 blk(256);

    // one fused cast for all 7 fp32->bf16 buffers (2048 elements per block)
    CastArgs ca;
    ca.s[0] = x;      ca.d[0] = xb;
    ca.s[1] = w_q;    ca.d[1] = wqb;
    ca.s[2] = w_qrot; ca.d[2] = wqrb;
    ca.s[3] = w_krot; ca.d[3] = wkrb;
    ca.s[4] = w_dkv;  ca.d[4] = wdkb;
    ca.s[5] = w_ukv;  ca.d[5] = wukb;
    ca.s[6] = w_o;    ca.d[6] = wob;
    ca.cum[0] = 0;
    ca.cum[1] = ca.cum[0] + 4096;   // x
    ca.cum[2] = ca.cum[1] + 2048;   // w_q
    ca.cum[3] = ca.cum[2] + 1024;   // w_qrot
    ca.cum[4] = ca.cum[3] + 64;     // w_krot
    ca.cum[5] = ca.cum[4] + 512;    // w_dkv
    ca.cum[6] = ca.cum[5] + 1024;   // w_ukv
    ca.cum[7] = ca.cum[6] + 2048;   // w_o
    cast_all<<<ca.cum[7], blk, 0, stream>>>(ca);

    // one consolidated projection GEMM: [q|qrot|krot|dkv] = xb @ wcat^T
    gemm_bt_256<__bf16><<<dim3(15, 16), dim3(512), 0, stream>>>(
        xb, 2048, wcat, qcat, 4096, QSTR, 2048);
    // ukv = dkv @ w_ukv^T  (A = strided dkv slice of qcat)
    gemm_bt_256<__bf16><<<dim3(16, 16), dim3(512), 0, stream>>>(
        qcat + 3136, QSTR, wukb, ukv, 4096, 4096, 512);

    rope_ip<<<8192, blk, 0, stream>>>(qcat + 2048, 9, QSTR, 4096 * 512);
    rope_ip<<<512,  blk, 0, stream>>>(qcat + 3072, 5, QSTR, 4096 * 32);
    prep_v<<<dim3(32, 32), blk, 0, stream>>>(ukv, vtt);

    flash_mfma<<<dim3(16, 32), blk, 0, stream>>>(qcat, ukv, vtt, ao);

    gemm_bt_8ph<float><<<dim3(8, 32), dim3(512), 0, stream>>>(
        ao, 2048, wob, out, 4096, 2048, 2048);
}